// Round 7
// baseline (2152.755 us; speedup 1.0000x reference)
//
#include <hip/hip_runtime.h>
#include <math.h>

// Mamba block, fp32, single-scan + closed-form seeding + fused epilogue.
// k_pre  : M = w_cls@w_out (10x82); transposed in_proj halves wTx/wTz into ws.
// k0_feat: features once + local scan -> per-pos (yloc, Dp, C), per-tile (P,H).
//          in_proj weights read from global (L1-hot, pre-transposed; LDS copy
//          removed -> 6 blocks/CU). feat records 768B, fully line-covered.
// k2_comb: sequential combine over tiles -> Hin per tile (carry across phases).
// k4_out : z-proj (global wTz), closed-form corr, gate, fused M-GEMM logits.
// OLD path (proven): fallback if ws too small.

namespace {
constexpr int DMODEL=41, DIN=82, NSTATE=16, NLAB=10, BATCH=32, SEQ=8192;
// old path
constexpr int CHUNK=512, NCHUNK=SEQ/CHUNK, TSUB=16, NSUB=CHUNK/TSUB, RWS=TSUB+3;
constexpr int XPAD=44, SPAD=83, CPAD=84, JPAD=36;
constexpr int NPH_OLD = BATCH*NCHUNK*DIN*NSTATE;
// new path
constexpr int T0 = 64;              // positions per k0/k4 tile
constexpr int FREC = 192;           // yloc@0(82) | Dp@82(82) | pad@164(12) | C@176(16)
inline size_t tier_bytes(int P){
  size_t SEG = (size_t)SEQ/P, tiles = SEG/T0;
  return ((size_t)BATCH*SEG*FREC + 3*((size_t)BATCH*tiles*1312)
          + (size_t)BATCH*1312 + 8192)*4;
}
}

__device__ __forceinline__ float siluf(float v)     { return v / (1.f + expf(-v)); }
__device__ __forceinline__ float softplusf(float v) { return (v > 20.f) ? v : log1pf(expf(v)); }
// fast variants (validated R4/R5: absmax unchanged at 5.96e-8)
__device__ __forceinline__ float silu_f(float v){
  return v * __builtin_amdgcn_rcpf(1.f + __expf(-v));
}
__device__ __forceinline__ float softplus_f(float v){
  return (v > 20.f) ? v : __logf(1.f + __expf(v));
}

// in_proj helper: NR rows from r0, col e(<82), weights wt[k*82+e] (global,
// L1-resident), x stride 44, out stride 82
template<int NR>
__device__ __forceinline__ void inproj_rows(int r0, int e,
    const float* __restrict__ sx, const float* __restrict__ wt,
    float* __restrict__ sxs) {
  float acc[NR];
#pragma unroll
  for (int i=0;i<NR;i++) acc[i]=0.f;
#pragma unroll
  for (int kq=0;kq<40;kq+=4){
    const float w0=wt[(kq+0)*82+e], w1=wt[(kq+1)*82+e];
    const float w2=wt[(kq+2)*82+e], w3=wt[(kq+3)*82+e];
#pragma unroll
    for (int i=0;i<NR;i++){
      const float4 xv = *(const float4*)&sx[(r0+i)*44+kq];
      acc[i]=fmaf(xv.x,w0,acc[i]); acc[i]=fmaf(xv.y,w1,acc[i]);
      acc[i]=fmaf(xv.z,w2,acc[i]); acc[i]=fmaf(xv.w,w3,acc[i]);
    }
  }
  const float wl = wt[40*82+e];
#pragma unroll
  for (int i=0;i<NR;i++)
    sxs[(r0+i)*82+e] = fmaf(sx[(r0+i)*44+40], wl, acc[i]);
}

// ============================================================================
// NEW PATH
// ============================================================================

__global__ __launch_bounds__(256) void k_pre(
    const float* __restrict__ w_out, const float* __restrict__ w_cls,
    const float* __restrict__ w_in,
    float* __restrict__ M, float* __restrict__ wTx, float* __restrict__ wTz){
  const int t0 = blockIdx.x*256 + threadIdx.x;
  const int stride = gridDim.x*256;
  for (int w=t0; w<NLAB*DIN; w+=stride){
    const int n = w/82, dd = w - n*82;
    float a = 0.f;
#pragma unroll
    for (int dm=0;dm<41;dm++) a = fmaf(w_cls[n*41+dm], w_out[dm*82+dd], a);
    M[w] = a;
  }
  for (int i=t0; i<41*82; i+=stride){
    const int k=i/82, e=i-k*82;
    wTx[i] = w_in[e*41+k];
    wTz[i] = w_in[(82+e)*41+k];
  }
}

__launch_bounds__(256, 6)
__global__ void k0_feat(
    const float* __restrict__ xg, const float* __restrict__ wTx,
    const float* __restrict__ w_conv, const float* __restrict__ b_conv,
    const float* __restrict__ w_xproj, const float* __restrict__ w_dt,
    const float* __restrict__ b_dt, const float* __restrict__ A_log,
    const float* __restrict__ Dvec, int off, int SEG,
    float* __restrict__ feat, float* __restrict__ Pg, float* __restrict__ Hg)
{
  __shared__ float s_x[19*44];    // raw x rows (pos p0-3 .. p0+15)
  __shared__ float s_xs[19*82];   // xs rows incl conv halo
  __shared__ float s_xc[16*82];   // xc
  __shared__ float s_q[16*82];    // delta
  __shared__ float s_db[16*36];   // dt@0..2, B@4..19, C@20..35
  __shared__ float s_cw[4*82];    // conv w transposed [k][d]
  __shared__ float s_dtw[3*82];   // dt w transposed [k][d]
  __shared__ float s_cb[82], s_dtb[82], s_A0[82], s_Dv[82];
  __shared__ int   s_flag[82];
  // ~25.7 KB -> 6 blocks/CU

  const int tid = threadIdx.x;
  const int tile = blockIdx.x, b = blockIdx.y;
  const int base_pos = off + tile*T0;

  for (int i=tid;i<328;i+=256){ int dd=i/4,k=i-dd*4; s_cw[k*82+dd]=w_conv[i]; }
  for (int i=tid;i<246;i+=256){ int dd=i/3,k=i-dd*3; s_dtw[k*82+dd]=w_dt[i]; }
  if (tid<82){
    s_cb[tid]=b_conv[tid]; s_dtb[tid]=b_dt[tid]; s_Dv[tid]=Dvec[tid];
    float A0=-expf(A_log[tid*16]); s_A0[tid]=A0;
    bool ok=(A0<0.f);
#pragma unroll
    for (int s=1;s<16;s++){
      float As=-expf(A_log[tid*16+s]);
      ok = ok && (fabsf(As-(float)(s+1)*A0) <= 1e-3f*(float)(s+1)*fabsf(A0));
    }
    s_flag[tid]=ok?1:0;
  }
  __syncthreads();

  const int d = tid>>1, sg = tid&1;
  float h[8], As[8], A0d=-1.f, Dp=0.f;
  int flag=1;
  if (tid<164){
    flag = s_flag[d]; A0d = s_A0[d];
    if (!flag){
#pragma unroll
      for (int i=0;i<8;i++) As[i]=-expf(A_log[d*16+sg*8+i]);
    }
#pragma unroll
    for (int i=0;i<8;i++) h[i]=0.f;
  }

  for (int it=0; it<T0/16; ++it){
    const int p0 = base_pos + it*16;
    // ---- A: halo shift + raw x load ----
    if (it>0){
      for (int i=tid;i<246;i+=256){ int r=i/82, dd=i-r*82; s_xs[r*82+dd]=s_xs[(16+r)*82+dd]; }
    }
    {
      const int rlo=(it==0)?0:3, cnt=(19-rlo)*41;
      for (int i=tid;i<cnt;i+=256){
        int r=rlo+i/41, k=i-(i/41)*41;
        int pos=p0-3+r;
        s_x[r*44+k] = (pos>=0) ? xg[((size_t)b*SEQ+(size_t)pos)*41+k] : 0.f;
      }
    }
    __syncthreads();
    // ---- B: in_proj (xs half), 2 threads/column, weights from global L1 ----
    if (tid<164){
      const int e=(tid<82)?tid:tid-82, rh=(tid>=82);
      if (it==0){ if(!rh) inproj_rows<10>(0,e,s_x,wTx,s_xs); else inproj_rows<9>(10,e,s_x,wTx,s_xs); }
      else      { inproj_rows<8>(rh?11:3,e,s_x,wTx,s_xs); }
    }
    __syncthreads();
    // ---- C: conv + silu -> s_xc ----
    for (int w=tid;w<1312;w+=256){
      const int l=w&15, dd=w>>4;
      float a=s_cb[dd];
#pragma unroll
      for (int k=0;k<4;k++) a=fmaf(s_xs[(l+k)*82+dd], s_cw[k*82+dd], a);
      s_xc[l*82+dd]=silu_f(a);
    }
    __syncthreads();
    // ---- D: x_proj (35 rows) -> dt/B/C (C also to feat) + pad zeroing ----
    for (int w=tid;w<560;w+=256){
      const int l=w&15, j=w>>4;
      const float2* wp=(const float2*)(w_xproj + j*82);
      const float2* gp=(const float2*)&s_xc[l*82];
      float a=0.f;
#pragma unroll
      for (int dq=0;dq<41;dq++){
        const float2 wv=wp[dq], gv=gp[dq];
        a=fmaf(wv.x,gv.x,a); a=fmaf(wv.y,gv.y,a);
      }
      const int col=(j<3)?j:j+1;
      s_db[l*36+col]=a;
      if (j>=19){
        feat[((size_t)b*SEG + (size_t)(tile*T0+it*16+l))*FREC + 176 + (j-19)] = a;
      }
    }
    for (int w=tid;w<192;w+=256){   // pad@164..175: keep every 64B line fully written
      const int l=w/12, pz=w-l*12;
      feat[((size_t)b*SEG + (size_t)(tile*T0+it*16+l))*FREC + 164 + pz] = 0.f;
    }
    __syncthreads();
    // ---- D2: dt_proj + softplus -> delta ----
    for (int w=tid;w<1312;w+=256){
      const int l=w&15, dd=w>>4;
      float a=s_dtb[dd];
      a=fmaf(s_db[l*36+0],s_dtw[0*82+dd],a);
      a=fmaf(s_db[l*36+1],s_dtw[1*82+dd],a);
      a=fmaf(s_db[l*36+2],s_dtw[2*82+dd],a);
      s_q[l*82+dd]=softplus_f(a);
    }
    __syncthreads();
    // ---- E: local scan with y; write yloc/Dp per position ----
    if (tid<164){
#pragma unroll 1
      for (int l=0;l<16;l++){
        const float dl  = s_q[l*82+d];
        const float xc  = s_xc[l*82+d];
        const float dxc = dl*xc;
        Dp += dl;
        const float4 B0=*(const float4*)&s_db[l*36+4+sg*8];
        const float4 B1=*(const float4*)&s_db[l*36+8+sg*8];
        const float4 C0=*(const float4*)&s_db[l*36+20+sg*8];
        const float4 C1=*(const float4*)&s_db[l*36+24+sg*8];
        const float Bv[8]={B0.x,B0.y,B0.z,B0.w,B1.x,B1.y,B1.z,B1.w};
        const float Cv[8]={C0.x,C0.y,C0.z,C0.w,C1.x,C1.y,C1.z,C1.w};
        float y=0.f;
        if (flag){
          const float q=__expf(dl*A0d);
          const float q2=q*q, q4=q2*q2;
          float e = sg ? q4*q4*q : q;
#pragma unroll
          for (int s=0;s<8;s++){
            h[s]=fmaf(e,h[s],dxc*Bv[s]);
            y=fmaf(h[s],Cv[s],y);
            if(s<7) e*=q;
          }
        } else {
#pragma unroll
          for (int s=0;s<8;s++){
            const float e=__expf(dl*As[s]);
            h[s]=fmaf(e,h[s],dxc*Bv[s]);
            y=fmaf(h[s],Cv[s],y);
          }
        }
        y += __shfl_down(y,1);
        if (sg==0){
          float* fp = feat + ((size_t)b*SEG + (size_t)(tile*T0+it*16+l))*FREC;
          fp[d]    = y + xc*s_Dv[d];
          fp[82+d] = Dp;
        }
      }
    }
    // no trailing barrier: stage A's sync protects s_xs halo readers
  }

  if (tid<164){
    float Pv[8];
    if (flag){
      const float Qt=__expf(Dp*A0d);
      const float Q2=Qt*Qt, Q4=Q2*Q2, Q8=Q4*Q4;
      float c = sg ? Q8*Qt : Qt;
#pragma unroll
      for (int i=0;i<8;i++){ Pv[i]=c; c*=Qt; }
    } else {
#pragma unroll
      for (int i=0;i<8;i++) Pv[i]=__expf(Dp*As[i]);
    }
    const size_t base = ((size_t)(b*gridDim.x+tile))*1312 + (size_t)d*16 + sg*8;
    *(float4*)&Pg[base]   = make_float4(Pv[0],Pv[1],Pv[2],Pv[3]);
    *(float4*)&Pg[base+4] = make_float4(Pv[4],Pv[5],Pv[6],Pv[7]);
    *(float4*)&Hg[base]   = make_float4(h[0],h[1],h[2],h[3]);
    *(float4*)&Hg[base+4] = make_float4(h[4],h[5],h[6],h[7]);
  }
}

__global__ __launch_bounds__(256) void k2_comb(
    const float* __restrict__ Pg, const float* __restrict__ Hg,
    float* __restrict__ Hin, float* __restrict__ carry, int TPP, int first)
{
  const int g = blockIdx.x*256 + threadIdx.x;   // < 32*1312
  const int b = g/1312, r = g - b*1312;
  float h = first ? 0.f : carry[g];
#pragma unroll 4
  for (int t=0;t<TPP;t++){
    const size_t idx = ((size_t)(b*TPP+t))*1312 + r;
    Hin[idx]=h;
    h = fmaf(Pg[idx], h, Hg[idx]);
  }
  carry[g]=h;
}

__launch_bounds__(256, 6)
__global__ void k4_out(
    const float* __restrict__ xg, const float* __restrict__ wTz,
    const float* __restrict__ A_log, const float* __restrict__ Mg,
    const float* __restrict__ b_cls, int off, int SEG,
    const float* __restrict__ feat, const float* __restrict__ Hin,
    float* __restrict__ outg)
{
  __shared__ float s_x[16*44];    // raw x rows
  __shared__ float s_z[16*82];    // silu(z)
  __shared__ float s_g[16*82];    // gated value
  __shared__ float s_c[16*16];    // C rows
  __shared__ float s_hin[1312];   // s-major [s*82+d]
  __shared__ float s_M[10*82];    // fused Wc*Wo
  __shared__ float s_A0[82], s_bc[10];
  __shared__ int   s_flag[82];
  // ~23.1 KB -> 6 blocks/CU

  const int tid = threadIdx.x;
  const int tile = blockIdx.x, b = blockIdx.y;

  for (int i=tid;i<1312;i+=256){
    const int dd=i>>4, s=i&15;
    s_hin[s*82+dd] = Hin[((size_t)(b*gridDim.x+tile))*1312 + i];
  }
  for (int i=tid;i<820;i+=256) s_M[i]=Mg[i];
  if (tid<10) s_bc[tid]=b_cls[tid];
  if (tid<82){
    float A0=-expf(A_log[tid*16]); s_A0[tid]=A0;
    bool ok=(A0<0.f);
#pragma unroll
    for (int s=1;s<16;s++){
      float As=-expf(A_log[tid*16+s]);
      ok = ok && (fabsf(As-(float)(s+1)*A0) <= 1e-3f*(float)(s+1)*fabsf(A0));
    }
    s_flag[tid]=ok?1:0;
  }
  // hoisted (l,d) decomposition for the 1312-item stage
  int lk[6], dk[6];
#pragma unroll
  for (int k=0;k<6;k++){ const int w=tid+256*k; lk[k]=w/82; dk[k]=w-lk[k]*82; }

  for (int it=0; it<T0/16; ++it){
    const int lp0 = tile*T0 + it*16;
    const int gp0 = off + lp0;
    __syncthreads();
    // ---- A: load raw x + C rows ----
    for (int i=tid;i<656;i+=256){
      const int r=i/41, k=i-r*41;
      s_x[r*44+k] = xg[((size_t)b*SEQ+(size_t)(gp0+r))*41+k];
    }
    for (int i=tid;i<64;i+=256){
      const int l=i>>2, q=i&3;
      ((float4*)&s_c[l*16])[q] =
          ((const float4*)(feat + ((size_t)b*SEG+(size_t)(lp0+l))*FREC + 176))[q];
    }
    __syncthreads();
    // ---- B: z-proj (global wTz), 2 threads/column, 8 rows -> silu ----
    if (tid<164){
      const int e=(tid<82)?tid:tid-82, l0=(tid>=82)?8:0;
      float acc[8];
#pragma unroll
      for (int i=0;i<8;i++) acc[i]=0.f;
#pragma unroll
      for (int kq=0;kq<40;kq+=4){
        const float w0=wTz[(kq+0)*82+e], w1=wTz[(kq+1)*82+e];
        const float w2=wTz[(kq+2)*82+e], w3=wTz[(kq+3)*82+e];
#pragma unroll
        for (int i=0;i<8;i++){
          const float4 xv=*(const float4*)&s_x[(l0+i)*44+kq];
          acc[i]=fmaf(xv.x,w0,acc[i]); acc[i]=fmaf(xv.y,w1,acc[i]);
          acc[i]=fmaf(xv.z,w2,acc[i]); acc[i]=fmaf(xv.w,w3,acc[i]);
        }
      }
      const float wl=wTz[40*82+e];
#pragma unroll
      for (int i=0;i<8;i++)
        s_z[(l0+i)*82+e] = silu_f(fmaf(s_x[(l0+i)*44+40], wl, acc[i]));
    }
    __syncthreads();
    // ---- C: closed-form correction + gate ----
#pragma unroll
    for (int k=0;k<6;k++){
      const int w=tid+256*k;
      if (w>=1312) break;
      const int l=lk[k], dd=dk[k];
      const float* fp = feat + ((size_t)b*SEG+(size_t)(lp0+l))*FREC;
      const float yl = fp[dd];
      const float Dp = fp[82+dd];
      float acc=yl;
      if (s_flag[dd]){
        const float Qt=__expf(s_A0[dd]*Dp);
        float e=Qt;
#pragma unroll
        for (int s=0;s<16;s++){
          acc = fmaf(s_c[l*16+s]*e, s_hin[s*82+dd], acc);
          if (s<15) e*=Qt;
        }
      } else {
#pragma unroll
        for (int s=0;s<16;s++){
          const float As = -__expf(A_log[dd*16+s]);
          acc = fmaf(s_c[l*16+s]*__expf(As*Dp), s_hin[s*82+dd], acc);
        }
      }
      s_g[l*82+dd] = acc * s_z[l*82+dd];
    }
    __syncthreads();
    // ---- D: fused logits = M*g + b, contiguous store ----
    if (tid<160){
      const int l=tid/10, n=tid-(tid/10)*10;
      float a=s_bc[n];
      const float2* gp=(const float2*)&s_g[l*82];
      const float2* mp=(const float2*)&s_M[n*82];
#pragma unroll
      for (int q=0;q<41;q++){
        const float2 gv=gp[q], mv=mp[q];
        a=fmaf(gv.x,mv.x,a); a=fmaf(gv.y,mv.y,a);
      }
      outg[((size_t)b*SEQ+(size_t)gp0)*10 + tid] = a;
    }
    // no trailing barrier: top-of-loop sync protects s_x/s_c overwrite
  }
}

// ============================================================================
// OLD PATH (proven fallback)
// ============================================================================

template <int PASS>
__launch_bounds__(256, 2)
__global__ void mamba_chunk(
    const float* __restrict__ xg, const float* __restrict__ w_in,
    const float* __restrict__ w_conv, const float* __restrict__ b_conv,
    const float* __restrict__ w_xproj, const float* __restrict__ w_dt,
    const float* __restrict__ b_dt, const float* __restrict__ A_log,
    const float* __restrict__ Dvec, const float* __restrict__ w_out,
    const float* __restrict__ w_cls, const float* __restrict__ b_cls,
    float* __restrict__ Pg, float* __restrict__ Hg,
    const float* __restrict__ Hin, float* __restrict__ outg)
{
  __shared__ float s_x[RWS*XPAD];
  __shared__ float s_xs[RWS*SPAD];
  __shared__ float s_xc[TSUB*CPAD];
  __shared__ float s_z[TSUB*SPAD];
  __shared__ float s_xdbc[TSUB*JPAD];
  __shared__ float w_in_t[DMODEL*164];
  __shared__ float w_xp_t[DIN*35];
  __shared__ float s_cw[DIN*4];
  __shared__ float s_cb[DIN];
  __shared__ float s_dtw[DIN*3];
  __shared__ float s_dtb[DIN];

  const int tid=threadIdx.x;
  const int b=blockIdx.x/NCHUNK, c=blockIdx.x%NCHUNK, l0c=c*CHUNK;
  constexpr int NJ=(PASS==3)?35:19;
  constexpr int NE=(PASS==3)?164:DIN;

  for (int i=tid;i<DMODEL*164;i+=256){ int k=i/164,e=i-k*164; w_in_t[i]=w_in[e*DMODEL+k]; }
  for (int i=tid;i<DIN*35;i+=256){ int dd=i/35,j=i-dd*35; w_xp_t[i]=w_xproj[j*DIN+dd]; }
  for (int i=tid;i<DIN*4;i+=256) s_cw[i]=w_conv[i];
  for (int i=tid;i<DIN*3;i+=256) s_dtw[i]=w_dt[i];
  if (tid<DIN){ s_cb[tid]=b_conv[tid]; s_dtb[tid]=b_dt[tid]; }

  float h[NSTATE], Pp[NSTATE], As[NSTATE];
  float A0=-1.f, Dd=0.f;
  bool structured=true;
  if (tid<DIN){
#pragma unroll
    for (int s=0;s<NSTATE;++s) As[s]=-expf(A_log[tid*NSTATE+s]);
    A0=As[0];
#pragma unroll
    for (int s=0;s<NSTATE;++s)
      structured = structured && (fabsf(As[s]-(float)(s+1)*A0)<=1e-3f*(float)(s+1)*fabsf(A0));
    structured = structured && (A0<0.f);
    if (PASS==3){
      Dd=Dvec[tid];
      size_t base=((size_t)(b*NCHUNK+c))*(DIN*NSTATE)+(size_t)tid*NSTATE;
#pragma unroll
      for (int s=0;s<NSTATE;++s) h[s]=Hin[base+s];
    } else {
#pragma unroll
      for (int s=0;s<NSTATE;++s){ h[s]=0.f; Pp[s]=1.f; }
    }
  }
  __syncthreads();

  for (int t=0;t<NSUB;++t){
    const int p0=l0c+t*TSUB;
    for (int i=tid;i<RWS*DMODEL;i+=256){
      int r=i/DMODEL,k=i-r*DMODEL;
      int pos=p0-3+r;
      s_x[r*XPAD+k]=(pos>=0)?xg[(size_t)b*SEQ*DMODEL+(size_t)pos*DMODEL+k]:0.f;
    }
    __syncthreads();
    {
      const int e=tid;
      if (e<NE){
        float acc[RWS];
#pragma unroll
        for (int r=0;r<RWS;++r) acc[r]=0.f;
#pragma unroll
        for (int kq=0;kq<40;kq+=4){
          const float w0=w_in_t[(kq+0)*164+e], w1=w_in_t[(kq+1)*164+e];
          const float w2=w_in_t[(kq+2)*164+e], w3=w_in_t[(kq+3)*164+e];
#pragma unroll
          for (int r=0;r<RWS;++r){
            const float4 xv=*(const float4*)&s_x[r*XPAD+kq];
            acc[r]=fmaf(xv.x,w0,acc[r]); acc[r]=fmaf(xv.y,w1,acc[r]);
            acc[r]=fmaf(xv.z,w2,acc[r]); acc[r]=fmaf(xv.w,w3,acc[r]);
          }
        }
        const float wl=w_in_t[40*164+e];
#pragma unroll
        for (int r=0;r<RWS;++r) acc[r]=fmaf(s_x[r*XPAD+40],wl,acc[r]);
        if (e<DIN){
#pragma unroll
          for (int r=0;r<RWS;++r) s_xs[r*SPAD+e]=acc[r];
        } else {
#pragma unroll
          for (int r=3;r<RWS;++r) s_z[(r-3)*SPAD+(e-DIN)]=acc[r];
        }
      }
    }
    __syncthreads();
    for (int w=tid;w<TSUB*DIN;w+=256){
      const int l=w&15,e=w>>4;
      float a=s_cb[e];
#pragma unroll
      for (int k=0;k<4;++k) a=fmaf(s_xs[(l+k)*SPAD+e],s_cw[e*4+k],a);
      s_xc[l*CPAD+e]=siluf(a);
    }
    __syncthreads();
    for (int w=tid;w<TSUB*NJ;w+=256){
      const int l=w&15,j=w>>4;
      float a=0.f;
#pragma unroll
      for (int dq=0;dq<80;dq+=4){
        const float4 xv=*(const float4*)&s_xc[l*CPAD+dq];
        a=fmaf(xv.x,w_xp_t[(dq+0)*35+j],a); a=fmaf(xv.y,w_xp_t[(dq+1)*35+j],a);
        a=fmaf(xv.z,w_xp_t[(dq+2)*35+j],a); a=fmaf(xv.w,w_xp_t[(dq+3)*35+j],a);
      }
      a=fmaf(s_xc[l*CPAD+80],w_xp_t[80*35+j],a);
      a=fmaf(s_xc[l*CPAD+81],w_xp_t[81*35+j],a);
      const int col=(j<3)?j:j+1;
      s_xdbc[l*JPAD+col]=a;
    }
    __syncthreads();
    for (int w=tid;w<TSUB*DIN;w+=256){
      const int l=w&15,dd=w>>4;
      float a=s_dtb[dd];
      a=fmaf(s_xdbc[l*JPAD+0],s_dtw[dd*3+0],a);
      a=fmaf(s_xdbc[l*JPAD+1],s_dtw[dd*3+1],a);
      a=fmaf(s_xdbc[l*JPAD+2],s_dtw[dd*3+2],a);
      s_xs[l*SPAD+dd]=softplusf(a);
    }
    __syncthreads();
    if (tid<DIN){
      const int dd=tid;
#pragma unroll 1
      for (int l=0;l<TSUB;++l){
        const float dl=s_xs[l*SPAD+dd];
        const float xcd=s_xc[l*CPAD+dd];
        const float dxc=dl*xcd;
        const float4 B0=*(const float4*)&s_xdbc[l*JPAD+4];
        const float4 B1=*(const float4*)&s_xdbc[l*JPAD+8];
        const float4 B2=*(const float4*)&s_xdbc[l*JPAD+12];
        const float4 B3=*(const float4*)&s_xdbc[l*JPAD+16];
        const float Bv[NSTATE]={B0.x,B0.y,B0.z,B0.w,B1.x,B1.y,B1.z,B1.w,
                                B2.x,B2.y,B2.z,B2.w,B3.x,B3.y,B3.z,B3.w};
        float Cv[NSTATE];
        if (PASS==3){
          const float4 C0=*(const float4*)&s_xdbc[l*JPAD+20];
          const float4 C1=*(const float4*)&s_xdbc[l*JPAD+24];
          const float4 C2=*(const float4*)&s_xdbc[l*JPAD+28];
          const float4 C3=*(const float4*)&s_xdbc[l*JPAD+32];
          Cv[0]=C0.x;Cv[1]=C0.y;Cv[2]=C0.z;Cv[3]=C0.w;
          Cv[4]=C1.x;Cv[5]=C1.y;Cv[6]=C1.z;Cv[7]=C1.w;
          Cv[8]=C2.x;Cv[9]=C2.y;Cv[10]=C2.z;Cv[11]=C2.w;
          Cv[12]=C3.x;Cv[13]=C3.y;Cv[14]=C3.z;Cv[15]=C3.w;
        }
        float y=(PASS==3)?Dd*xcd:0.f;
        if (structured){
          const float q=expf(dl*A0);
          float e=q;
#pragma unroll
          for (int s=0;s<NSTATE;++s){
            h[s]=fmaf(e,h[s],dxc*Bv[s]);
            if (PASS==1) Pp[s]*=e; else y=fmaf(h[s],Cv[s],y);
            if (s<NSTATE-1) e*=q;
          }
        } else {
#pragma unroll
          for (int s=0;s<NSTATE;++s){
            const float e=expf(dl*As[s]);
            h[s]=fmaf(e,h[s],dxc*Bv[s]);
            if (PASS==1) Pp[s]*=e; else y=fmaf(h[s],Cv[s],y);
          }
        }
        if (PASS==3) s_xs[l*SPAD+dd]=y;
      }
    }
    __syncthreads();
    if (PASS==3){
      for (int w=tid;w<TSUB*DIN;w+=256){
        const int l=w&15,dd=w>>4;
        s_xc[l*CPAD+dd]=s_xs[l*SPAD+dd]*siluf(s_z[l*SPAD+dd]);
      }
      __syncthreads();
      for (int w=tid;w<TSUB*DMODEL;w+=256){
        const int l=w&15,dm=w>>4;
        const float2* wp=(const float2*)(w_out+dm*DIN);
        const float2* gp=(const float2*)&s_xc[l*CPAD];
        float a=0.f;
#pragma unroll
        for (int dq=0;dq<41;++dq){
          const float2 wv=wp[dq], gv=gp[dq];
          a=fmaf(wv.x,gv.x,a); a=fmaf(wv.y,gv.y,a);
        }
        s_x[l*XPAD+dm]=a;
      }
      __syncthreads();
      for (int w=tid;w<TSUB*NLAB;w+=256){
        const int l=w&15,n=w>>4;
        float a=b_cls[n];
#pragma unroll
        for (int dm=0;dm<DMODEL;++dm) a=fmaf(w_cls[n*DMODEL+dm],s_x[l*XPAD+dm],a);
        s_xdbc[l*NLAB+n]=a;
      }
      __syncthreads();
      for (int i=tid;i<TSUB*NLAB;i+=256)
        outg[((size_t)(b*SEQ+p0))*NLAB+i]=s_xdbc[i];
      __syncthreads();
    }
  }

  if (PASS==1 && tid<DIN){
    size_t base=((size_t)(b*NCHUNK+c))*(DIN*NSTATE)+(size_t)tid*NSTATE;
#pragma unroll
    for (int s=0;s<NSTATE;++s){ Pg[base+s]=Pp[s]; Hg[base+s]=h[s]; }
  }
}

__global__ __launch_bounds__(256) void mamba_combine(
    const float* __restrict__ P, const float* __restrict__ H, float* __restrict__ Hin){
  const int g=blockIdx.x*256+threadIdx.x;
  const int b=g/(DIN*NSTATE), ds=g-b*(DIN*NSTATE);
  float h=0.f;
#pragma unroll 1
  for (int c=0;c<NCHUNK;++c){
    const size_t idx=((size_t)(b*NCHUNK+c))*(DIN*NSTATE)+ds;
    Hin[idx]=h;
    h=fmaf(P[idx],h,H[idx]);
  }
}

// ============================================================================

extern "C" void kernel_launch(void* const* d_in, const int* in_sizes, int n_in,
                              void* d_out, int out_size, void* d_ws, size_t ws_size,
                              hipStream_t stream) {
  const float* xg     = (const float*)d_in[0];
  const float* w_in   = (const float*)d_in[1];
  const float* w_conv = (const float*)d_in[2];
  const float* b_conv = (const float*)d_in[3];
  const float* w_xp   = (const float*)d_in[4];
  const float* w_dt   = (const float*)d_in[5];
  const float* b_dt   = (const float*)d_in[6];
  const float* A_log  = (const float*)d_in[7];
  const float* Dv     = (const float*)d_in[8];
  const float* w_out  = (const float*)d_in[9];
  const float* w_cls  = (const float*)d_in[10];
  const float* b_cls  = (const float*)d_in[11];
  float* outg = (float*)d_out;

  int P = 0;
  for (int p : {1,2,4,8}) if (ws_size >= tier_bytes(p)) { P = p; break; }

  if (P) {
    const int SEG = SEQ/P, tiles = SEG/T0;
    const size_t featF = (size_t)BATCH*SEG*FREC;
    const size_t phF   = (size_t)BATCH*tiles*1312;
    float* feat  = (float*)d_ws;
    float* Pg    = feat + featF;
    float* Hg    = Pg + phF;
    float* Hin   = Hg + phF;
    float* carry = Hin + phF;
    float* Mg    = carry + (size_t)BATCH*1312;
    float* wTx   = Mg + 820;
    float* wTz   = wTx + 3362;
    k_pre<<<dim3(32),256,0,stream>>>(w_out, w_cls, w_in, Mg, wTx, wTz);
    for (int p=0;p<P;p++){
      const int off = p*SEG;
      k0_feat<<<dim3(tiles,BATCH),256,0,stream>>>(
          xg,wTx,w_conv,b_conv,w_xp,w_dt,b_dt,A_log,Dv,off,SEG,feat,Pg,Hg);
      k2_comb<<<dim3((BATCH*1312)/256),256,0,stream>>>(Pg,Hg,Hin,carry,tiles,p==0?1:0);
      k4_out<<<dim3(tiles,BATCH),256,0,stream>>>(
          xg,wTz,A_log,Mg,b_cls,off,SEG,feat,Hin,outg);
    }
  } else {
    float* Pg  = (float*)d_ws;
    float* Hg  = Pg + NPH_OLD;
    float* Hin = Hg + NPH_OLD;
    dim3 grid(BATCH*NCHUNK), blk(256);
    mamba_chunk<1><<<grid,blk,0,stream>>>(xg,w_in,w_conv,b_conv,w_xp,w_dt,b_dt,
                                          A_log,Dv,w_out,w_cls,b_cls,Pg,Hg,nullptr,nullptr);
    mamba_combine<<<dim3((BATCH*DIN*NSTATE)/256),blk,0,stream>>>(Pg,Hg,Hin);
    mamba_chunk<3><<<grid,blk,0,stream>>>(xg,w_in,w_conv,b_conv,w_xp,w_dt,b_dt,
                                          A_log,Dv,w_out,w_cls,b_cls,nullptr,nullptr,Hin,outg);
  }
}

// Round 8
// 1245.436 us; speedup vs baseline: 1.7285x; 1.7285x over previous
//
#include <hip/hip_runtime.h>
#include <math.h>

// Mamba block, fp32, single-scan + closed-form seeding + fused epilogue.
// k_pre  : M = w_cls@w_out (10x82); transposed in_proj halves wTx/wTz into ws.
// k0_feat: features once + local scan -> per-pos (yloc, Dp, C), per-tile (P,H).
// k2_comb: sequential combine over tiles -> Hin per tile (carry across phases).
// k4_out : z-proj (global wTz), closed-form corr, gate, fused M-GEMM logits.
// LAUNCH BOUNDS: (256,4) ONLY. (256,6) caps VGPRs at ~85 -> allocator hit 40
// -> scan state spilled -> 3.3GB scratch traffic (R6, 2.2x regression).
// Reg-array weights also spill (R4). 64 VGPR natural fit needs min-waves<=4.
// OLD path (proven): fallback if ws too small.

namespace {
constexpr int DMODEL=41, DIN=82, NSTATE=16, NLAB=10, BATCH=32, SEQ=8192;
// old path
constexpr int CHUNK=512, NCHUNK=SEQ/CHUNK, TSUB=16, NSUB=CHUNK/TSUB, RWS=TSUB+3;
constexpr int XPAD=44, SPAD=83, CPAD=84, JPAD=36;
constexpr int NPH_OLD = BATCH*NCHUNK*DIN*NSTATE;
// new path
constexpr int T0 = 64;              // positions per k0/k4 tile
constexpr int FREC = 192;           // yloc@0(82) | Dp@82(82) | pad@164(12) | C@176(16)
inline size_t tier_bytes(int P){
  size_t SEG = (size_t)SEQ/P, tiles = SEG/T0;
  return ((size_t)BATCH*SEG*FREC + 3*((size_t)BATCH*tiles*1312)
          + (size_t)BATCH*1312 + 8192)*4;
}
}

__device__ __forceinline__ float siluf(float v)     { return v / (1.f + expf(-v)); }
__device__ __forceinline__ float softplusf(float v) { return (v > 20.f) ? v : log1pf(expf(v)); }
// fast variants (validated R4/R5: absmax unchanged at 5.96e-8)
__device__ __forceinline__ float silu_f(float v){
  return v * __builtin_amdgcn_rcpf(1.f + __expf(-v));
}
__device__ __forceinline__ float softplus_f(float v){
  return (v > 20.f) ? v : __logf(1.f + __expf(v));
}

// in_proj helper: NR rows from r0, col e(<82), weights wt[k*82+e] (global,
// L1-resident), x stride 44, out stride 82
template<int NR>
__device__ __forceinline__ void inproj_rows(int r0, int e,
    const float* __restrict__ sx, const float* __restrict__ wt,
    float* __restrict__ sxs) {
  float acc[NR];
#pragma unroll
  for (int i=0;i<NR;i++) acc[i]=0.f;
#pragma unroll
  for (int kq=0;kq<40;kq+=4){
    const float w0=wt[(kq+0)*82+e], w1=wt[(kq+1)*82+e];
    const float w2=wt[(kq+2)*82+e], w3=wt[(kq+3)*82+e];
#pragma unroll
    for (int i=0;i<NR;i++){
      const float4 xv = *(const float4*)&sx[(r0+i)*44+kq];
      acc[i]=fmaf(xv.x,w0,acc[i]); acc[i]=fmaf(xv.y,w1,acc[i]);
      acc[i]=fmaf(xv.z,w2,acc[i]); acc[i]=fmaf(xv.w,w3,acc[i]);
    }
  }
  const float wl = wt[40*82+e];
#pragma unroll
  for (int i=0;i<NR;i++)
    sxs[(r0+i)*82+e] = fmaf(sx[(r0+i)*44+40], wl, acc[i]);
}

// ============================================================================
// NEW PATH
// ============================================================================

__global__ __launch_bounds__(256) void k_pre(
    const float* __restrict__ w_out, const float* __restrict__ w_cls,
    const float* __restrict__ w_in,
    float* __restrict__ M, float* __restrict__ wTx, float* __restrict__ wTz){
  const int t0 = blockIdx.x*256 + threadIdx.x;
  const int stride = gridDim.x*256;
  for (int w=t0; w<NLAB*DIN; w+=stride){
    const int n = w/82, dd = w - n*82;
    float a = 0.f;
#pragma unroll
    for (int dm=0;dm<41;dm++) a = fmaf(w_cls[n*41+dm], w_out[dm*82+dd], a);
    M[w] = a;
  }
  for (int i=t0; i<41*82; i+=stride){
    const int k=i/82, e=i-k*82;
    wTx[i] = w_in[e*41+k];
    wTz[i] = w_in[(82+e)*41+k];
  }
}

__launch_bounds__(256, 4)
__global__ void k0_feat(
    const float* __restrict__ xg, const float* __restrict__ wTx,
    const float* __restrict__ w_conv, const float* __restrict__ b_conv,
    const float* __restrict__ w_xproj, const float* __restrict__ w_dt,
    const float* __restrict__ b_dt, const float* __restrict__ A_log,
    const float* __restrict__ Dvec, int off, int SEG,
    float* __restrict__ feat, float* __restrict__ Pg, float* __restrict__ Hg)
{
  __shared__ float s_x[19*44];    // raw x rows (pos p0-3 .. p0+15)
  __shared__ float s_xs[19*82];   // xs rows incl conv halo
  __shared__ float s_xc[16*82];   // xc
  __shared__ float s_q[16*82];    // delta
  __shared__ float s_db[16*36];   // dt@0..2, B@4..19, C@20..35
  __shared__ float s_cw[4*82];    // conv w transposed [k][d]
  __shared__ float s_dtw[3*82];   // dt w transposed [k][d]
  __shared__ float s_cb[82], s_dtb[82], s_A0[82], s_Dv[82];
  __shared__ int   s_flag[82];
  // ~25.7 KB -> LDS allows 6 blocks/CU; VGPR ~64 allows it too

  const int tid = threadIdx.x;
  const int tile = blockIdx.x, b = blockIdx.y;
  const int base_pos = off + tile*T0;

  for (int i=tid;i<328;i+=256){ int dd=i/4,k=i-dd*4; s_cw[k*82+dd]=w_conv[i]; }
  for (int i=tid;i<246;i+=256){ int dd=i/3,k=i-dd*3; s_dtw[k*82+dd]=w_dt[i]; }
  if (tid<82){
    s_cb[tid]=b_conv[tid]; s_dtb[tid]=b_dt[tid]; s_Dv[tid]=Dvec[tid];
    float A0=-expf(A_log[tid*16]); s_A0[tid]=A0;
    bool ok=(A0<0.f);
#pragma unroll
    for (int s=1;s<16;s++){
      float As=-expf(A_log[tid*16+s]);
      ok = ok && (fabsf(As-(float)(s+1)*A0) <= 1e-3f*(float)(s+1)*fabsf(A0));
    }
    s_flag[tid]=ok?1:0;
  }
  __syncthreads();

  const int d = tid>>1, sg = tid&1;
  float h[8], As[8], A0d=-1.f, Dp=0.f;
  int flag=1;
  if (tid<164){
    flag = s_flag[d]; A0d = s_A0[d];
    if (!flag){
#pragma unroll
      for (int i=0;i<8;i++) As[i]=-expf(A_log[d*16+sg*8+i]);
    }
#pragma unroll
    for (int i=0;i<8;i++) h[i]=0.f;
  }

  for (int it=0; it<T0/16; ++it){
    const int p0 = base_pos + it*16;
    // ---- A: halo shift + raw x load ----
    if (it>0){
      for (int i=tid;i<246;i+=256){ int r=i/82, dd=i-r*82; s_xs[r*82+dd]=s_xs[(16+r)*82+dd]; }
    }
    {
      const int rlo=(it==0)?0:3, cnt=(19-rlo)*41;
      for (int i=tid;i<cnt;i+=256){
        int r=rlo+i/41, k=i-(i/41)*41;
        int pos=p0-3+r;
        s_x[r*44+k] = (pos>=0) ? xg[((size_t)b*SEQ+(size_t)pos)*41+k] : 0.f;
      }
    }
    __syncthreads();
    // ---- B: in_proj (xs half), 2 threads/column, weights from global L1 ----
    if (tid<164){
      const int e=(tid<82)?tid:tid-82, rh=(tid>=82);
      if (it==0){ if(!rh) inproj_rows<10>(0,e,s_x,wTx,s_xs); else inproj_rows<9>(10,e,s_x,wTx,s_xs); }
      else      { inproj_rows<8>(rh?11:3,e,s_x,wTx,s_xs); }
    }
    __syncthreads();
    // ---- C: conv + silu -> s_xc ----
    for (int w=tid;w<1312;w+=256){
      const int l=w&15, dd=w>>4;
      float a=s_cb[dd];
#pragma unroll
      for (int k=0;k<4;k++) a=fmaf(s_xs[(l+k)*82+dd], s_cw[k*82+dd], a);
      s_xc[l*82+dd]=silu_f(a);
    }
    __syncthreads();
    // ---- D: x_proj (35 rows) -> dt/B/C (C also to feat) + pad zeroing ----
    for (int w=tid;w<560;w+=256){
      const int l=w&15, j=w>>4;
      const float2* wp=(const float2*)(w_xproj + j*82);
      const float2* gp=(const float2*)&s_xc[l*82];
      float a=0.f;
#pragma unroll
      for (int dq=0;dq<41;dq++){
        const float2 wv=wp[dq], gv=gp[dq];
        a=fmaf(wv.x,gv.x,a); a=fmaf(wv.y,gv.y,a);
      }
      const int col=(j<3)?j:j+1;
      s_db[l*36+col]=a;
      if (j>=19){
        feat[((size_t)b*SEG + (size_t)(tile*T0+it*16+l))*FREC + 176 + (j-19)] = a;
      }
    }
    for (int w=tid;w<192;w+=256){   // pad@164..175: keep every 64B line fully written
      const int l=w/12, pz=w-l*12;
      feat[((size_t)b*SEG + (size_t)(tile*T0+it*16+l))*FREC + 164 + pz] = 0.f;
    }
    __syncthreads();
    // ---- D2: dt_proj + softplus -> delta ----
    for (int w=tid;w<1312;w+=256){
      const int l=w&15, dd=w>>4;
      float a=s_dtb[dd];
      a=fmaf(s_db[l*36+0],s_dtw[0*82+dd],a);
      a=fmaf(s_db[l*36+1],s_dtw[1*82+dd],a);
      a=fmaf(s_db[l*36+2],s_dtw[2*82+dd],a);
      s_q[l*82+dd]=softplus_f(a);
    }
    __syncthreads();
    // ---- E: local scan with y; write yloc/Dp per position ----
    if (tid<164){
#pragma unroll 1
      for (int l=0;l<16;l++){
        const float dl  = s_q[l*82+d];
        const float xc  = s_xc[l*82+d];
        const float dxc = dl*xc;
        Dp += dl;
        const float4 B0=*(const float4*)&s_db[l*36+4+sg*8];
        const float4 B1=*(const float4*)&s_db[l*36+8+sg*8];
        const float4 C0=*(const float4*)&s_db[l*36+20+sg*8];
        const float4 C1=*(const float4*)&s_db[l*36+24+sg*8];
        const float Bv[8]={B0.x,B0.y,B0.z,B0.w,B1.x,B1.y,B1.z,B1.w};
        const float Cv[8]={C0.x,C0.y,C0.z,C0.w,C1.x,C1.y,C1.z,C1.w};
        float y=0.f;
        if (flag){
          const float q=__expf(dl*A0d);
          const float q2=q*q, q4=q2*q2;
          float e = sg ? q4*q4*q : q;
#pragma unroll
          for (int s=0;s<8;s++){
            h[s]=fmaf(e,h[s],dxc*Bv[s]);
            y=fmaf(h[s],Cv[s],y);
            if(s<7) e*=q;
          }
        } else {
#pragma unroll
          for (int s=0;s<8;s++){
            const float e=__expf(dl*As[s]);
            h[s]=fmaf(e,h[s],dxc*Bv[s]);
            y=fmaf(h[s],Cv[s],y);
          }
        }
        y += __shfl_down(y,1);
        if (sg==0){
          float* fp = feat + ((size_t)b*SEG + (size_t)(tile*T0+it*16+l))*FREC;
          fp[d]    = y + xc*s_Dv[d];
          fp[82+d] = Dp;
        }
      }
    }
    // no trailing barrier: stage A's sync protects s_xs halo readers
  }

  if (tid<164){
    float Pv[8];
    if (flag){
      const float Qt=__expf(Dp*A0d);
      const float Q2=Qt*Qt, Q4=Q2*Q2, Q8=Q4*Q4;
      float c = sg ? Q8*Qt : Qt;
#pragma unroll
      for (int i=0;i<8;i++){ Pv[i]=c; c*=Qt; }
    } else {
#pragma unroll
      for (int i=0;i<8;i++) Pv[i]=__expf(Dp*As[i]);
    }
    const size_t base = ((size_t)(b*gridDim.x+tile))*1312 + (size_t)d*16 + sg*8;
    *(float4*)&Pg[base]   = make_float4(Pv[0],Pv[1],Pv[2],Pv[3]);
    *(float4*)&Pg[base+4] = make_float4(Pv[4],Pv[5],Pv[6],Pv[7]);
    *(float4*)&Hg[base]   = make_float4(h[0],h[1],h[2],h[3]);
    *(float4*)&Hg[base+4] = make_float4(h[4],h[5],h[6],h[7]);
  }
}

__global__ __launch_bounds__(256) void k2_comb(
    const float* __restrict__ Pg, const float* __restrict__ Hg,
    float* __restrict__ Hin, float* __restrict__ carry, int TPP, int first)
{
  const int g = blockIdx.x*256 + threadIdx.x;   // < 32*1312
  const int b = g/1312, r = g - b*1312;
  float h = first ? 0.f : carry[g];
#pragma unroll 4
  for (int t=0;t<TPP;t++){
    const size_t idx = ((size_t)(b*TPP+t))*1312 + r;
    Hin[idx]=h;
    h = fmaf(Pg[idx], h, Hg[idx]);
  }
  carry[g]=h;
}

__launch_bounds__(256, 4)
__global__ void k4_out(
    const float* __restrict__ xg, const float* __restrict__ wTz,
    const float* __restrict__ A_log, const float* __restrict__ Mg,
    const float* __restrict__ b_cls, int off, int SEG,
    const float* __restrict__ feat, const float* __restrict__ Hin,
    float* __restrict__ outg)
{
  __shared__ float s_x[16*44];    // raw x rows
  __shared__ float s_z[16*82];    // silu(z)
  __shared__ float s_g[16*82];    // gated value
  __shared__ float s_c[16*16];    // C rows
  __shared__ float s_hin[1312];   // s-major [s*82+d]
  __shared__ float s_M[10*82];    // fused Wc*Wo
  __shared__ float s_A0[82], s_bc[10];
  __shared__ int   s_flag[82];
  // ~23.1 KB

  const int tid = threadIdx.x;
  const int tile = blockIdx.x, b = blockIdx.y;

  for (int i=tid;i<1312;i+=256){
    const int dd=i>>4, s=i&15;
    s_hin[s*82+dd] = Hin[((size_t)(b*gridDim.x+tile))*1312 + i];
  }
  for (int i=tid;i<820;i+=256) s_M[i]=Mg[i];
  if (tid<10) s_bc[tid]=b_cls[tid];
  if (tid<82){
    float A0=-expf(A_log[tid*16]); s_A0[tid]=A0;
    bool ok=(A0<0.f);
#pragma unroll
    for (int s=1;s<16;s++){
      float As=-expf(A_log[tid*16+s]);
      ok = ok && (fabsf(As-(float)(s+1)*A0) <= 1e-3f*(float)(s+1)*fabsf(A0));
    }
    s_flag[tid]=ok?1:0;
  }
  // hoisted (l,d) decomposition for the 1312-item stage
  int lk[6], dk[6];
#pragma unroll
  for (int k=0;k<6;k++){ const int w=tid+256*k; lk[k]=w/82; dk[k]=w-lk[k]*82; }

  for (int it=0; it<T0/16; ++it){
    const int lp0 = tile*T0 + it*16;
    const int gp0 = off + lp0;
    __syncthreads();
    // ---- A: load raw x + C rows ----
    for (int i=tid;i<656;i+=256){
      const int r=i/41, k=i-r*41;
      s_x[r*44+k] = xg[((size_t)b*SEQ+(size_t)(gp0+r))*41+k];
    }
    for (int i=tid;i<64;i+=256){
      const int l=i>>2, q=i&3;
      ((float4*)&s_c[l*16])[q] =
          ((const float4*)(feat + ((size_t)b*SEG+(size_t)(lp0+l))*FREC + 176))[q];
    }
    __syncthreads();
    // ---- B: z-proj (global wTz), 2 threads/column, 8 rows -> silu ----
    if (tid<164){
      const int e=(tid<82)?tid:tid-82, l0=(tid>=82)?8:0;
      float acc[8];
#pragma unroll
      for (int i=0;i<8;i++) acc[i]=0.f;
#pragma unroll
      for (int kq=0;kq<40;kq+=4){
        const float w0=wTz[(kq+0)*82+e], w1=wTz[(kq+1)*82+e];
        const float w2=wTz[(kq+2)*82+e], w3=wTz[(kq+3)*82+e];
#pragma unroll
        for (int i=0;i<8;i++){
          const float4 xv=*(const float4*)&s_x[(l0+i)*44+kq];
          acc[i]=fmaf(xv.x,w0,acc[i]); acc[i]=fmaf(xv.y,w1,acc[i]);
          acc[i]=fmaf(xv.z,w2,acc[i]); acc[i]=fmaf(xv.w,w3,acc[i]);
        }
      }
      const float wl=wTz[40*82+e];
#pragma unroll
      for (int i=0;i<8;i++)
        s_z[(l0+i)*82+e] = silu_f(fmaf(s_x[(l0+i)*44+40], wl, acc[i]));
    }
    __syncthreads();
    // ---- C: closed-form correction + gate ----
#pragma unroll
    for (int k=0;k<6;k++){
      const int w=tid+256*k;
      if (w>=1312) break;
      const int l=lk[k], dd=dk[k];
      const float* fp = feat + ((size_t)b*SEG+(size_t)(lp0+l))*FREC;
      const float yl = fp[dd];
      const float Dp = fp[82+dd];
      float acc=yl;
      if (s_flag[dd]){
        const float Qt=__expf(s_A0[dd]*Dp);
        float e=Qt;
#pragma unroll
        for (int s=0;s<16;s++){
          acc = fmaf(s_c[l*16+s]*e, s_hin[s*82+dd], acc);
          if (s<15) e*=Qt;
        }
      } else {
#pragma unroll
        for (int s=0;s<16;s++){
          const float As = -__expf(A_log[dd*16+s]);
          acc = fmaf(s_c[l*16+s]*__expf(As*Dp), s_hin[s*82+dd], acc);
        }
      }
      s_g[l*82+dd] = acc * s_z[l*82+dd];
    }
    __syncthreads();
    // ---- D: fused logits = M*g + b, contiguous store ----
    if (tid<160){
      const int l=tid/10, n=tid-(tid/10)*10;
      float a=s_bc[n];
      const float2* gp=(const float2*)&s_g[l*82];
      const float2* mp=(const float2*)&s_M[n*82];
#pragma unroll
      for (int q=0;q<41;q++){
        const float2 gv=gp[q], mv=mp[q];
        a=fmaf(gv.x,mv.x,a); a=fmaf(gv.y,mv.y,a);
      }
      outg[((size_t)b*SEQ+(size_t)gp0)*10 + tid] = a;
    }
    // no trailing barrier: top-of-loop sync protects s_x/s_c overwrite
  }
}

// ============================================================================
// OLD PATH (proven fallback)
// ============================================================================

template <int PASS>
__launch_bounds__(256, 2)
__global__ void mamba_chunk(
    const float* __restrict__ xg, const float* __restrict__ w_in,
    const float* __restrict__ w_conv, const float* __restrict__ b_conv,
    const float* __restrict__ w_xproj, const float* __restrict__ w_dt,
    const float* __restrict__ b_dt, const float* __restrict__ A_log,
    const float* __restrict__ Dvec, const float* __restrict__ w_out,
    const float* __restrict__ w_cls, const float* __restrict__ b_cls,
    float* __restrict__ Pg, float* __restrict__ Hg,
    const float* __restrict__ Hin, float* __restrict__ outg)
{
  __shared__ float s_x[RWS*XPAD];
  __shared__ float s_xs[RWS*SPAD];
  __shared__ float s_xc[TSUB*CPAD];
  __shared__ float s_z[TSUB*SPAD];
  __shared__ float s_xdbc[TSUB*JPAD];
  __shared__ float w_in_t[DMODEL*164];
  __shared__ float w_xp_t[DIN*35];
  __shared__ float s_cw[DIN*4];
  __shared__ float s_cb[DIN];
  __shared__ float s_dtw[DIN*3];
  __shared__ float s_dtb[DIN];

  const int tid=threadIdx.x;
  const int b=blockIdx.x/NCHUNK, c=blockIdx.x%NCHUNK, l0c=c*CHUNK;
  constexpr int NJ=(PASS==3)?35:19;
  constexpr int NE=(PASS==3)?164:DIN;

  for (int i=tid;i<DMODEL*164;i+=256){ int k=i/164,e=i-k*164; w_in_t[i]=w_in[e*DMODEL+k]; }
  for (int i=tid;i<DIN*35;i+=256){ int dd=i/35,j=i-dd*35; w_xp_t[i]=w_xproj[j*DIN+dd]; }
  for (int i=tid;i<DIN*4;i+=256) s_cw[i]=w_conv[i];
  for (int i=tid;i<DIN*3;i+=256) s_dtw[i]=w_dt[i];
  if (tid<DIN){ s_cb[tid]=b_conv[tid]; s_dtb[tid]=b_dt[tid]; }

  float h[NSTATE], Pp[NSTATE], As[NSTATE];
  float A0=-1.f, Dd=0.f;
  bool structured=true;
  if (tid<DIN){
#pragma unroll
    for (int s=0;s<NSTATE;++s) As[s]=-expf(A_log[tid*NSTATE+s]);
    A0=As[0];
#pragma unroll
    for (int s=0;s<NSTATE;++s)
      structured = structured && (fabsf(As[s]-(float)(s+1)*A0)<=1e-3f*(float)(s+1)*fabsf(A0));
    structured = structured && (A0<0.f);
    if (PASS==3){
      Dd=Dvec[tid];
      size_t base=((size_t)(b*NCHUNK+c))*(DIN*NSTATE)+(size_t)tid*NSTATE;
#pragma unroll
      for (int s=0;s<NSTATE;++s) h[s]=Hin[base+s];
    } else {
#pragma unroll
      for (int s=0;s<NSTATE;++s){ h[s]=0.f; Pp[s]=1.f; }
    }
  }
  __syncthreads();

  for (int t=0;t<NSUB;++t){
    const int p0=l0c+t*TSUB;
    for (int i=tid;i<RWS*DMODEL;i+=256){
      int r=i/DMODEL,k=i-r*DMODEL;
      int pos=p0-3+r;
      s_x[r*XPAD+k]=(pos>=0)?xg[(size_t)b*SEQ*DMODEL+(size_t)pos*DMODEL+k]:0.f;
    }
    __syncthreads();
    {
      const int e=tid;
      if (e<NE){
        float acc[RWS];
#pragma unroll
        for (int r=0;r<RWS;++r) acc[r]=0.f;
#pragma unroll
        for (int kq=0;kq<40;kq+=4){
          const float w0=w_in_t[(kq+0)*164+e], w1=w_in_t[(kq+1)*164+e];
          const float w2=w_in_t[(kq+2)*164+e], w3=w_in_t[(kq+3)*164+e];
#pragma unroll
          for (int r=0;r<RWS;++r){
            const float4 xv=*(const float4*)&s_x[r*XPAD+kq];
            acc[r]=fmaf(xv.x,w0,acc[r]); acc[r]=fmaf(xv.y,w1,acc[r]);
            acc[r]=fmaf(xv.z,w2,acc[r]); acc[r]=fmaf(xv.w,w3,acc[r]);
          }
        }
        const float wl=w_in_t[40*164+e];
#pragma unroll
        for (int r=0;r<RWS;++r) acc[r]=fmaf(s_x[r*XPAD+40],wl,acc[r]);
        if (e<DIN){
#pragma unroll
          for (int r=0;r<RWS;++r) s_xs[r*SPAD+e]=acc[r];
        } else {
#pragma unroll
          for (int r=3;r<RWS;++r) s_z[(r-3)*SPAD+(e-DIN)]=acc[r];
        }
      }
    }
    __syncthreads();
    for (int w=tid;w<TSUB*DIN;w+=256){
      const int l=w&15,e=w>>4;
      float a=s_cb[e];
#pragma unroll
      for (int k=0;k<4;++k) a=fmaf(s_xs[(l+k)*SPAD+e],s_cw[e*4+k],a);
      s_xc[l*CPAD+e]=siluf(a);
    }
    __syncthreads();
    for (int w=tid;w<TSUB*NJ;w+=256){
      const int l=w&15,j=w>>4;
      float a=0.f;
#pragma unroll
      for (int dq=0;dq<80;dq+=4){
        const float4 xv=*(const float4*)&s_xc[l*CPAD+dq];
        a=fmaf(xv.x,w_xp_t[(dq+0)*35+j],a); a=fmaf(xv.y,w_xp_t[(dq+1)*35+j],a);
        a=fmaf(xv.z,w_xp_t[(dq+2)*35+j],a); a=fmaf(xv.w,w_xp_t[(dq+3)*35+j],a);
      }
      a=fmaf(s_xc[l*CPAD+80],w_xp_t[80*35+j],a);
      a=fmaf(s_xc[l*CPAD+81],w_xp_t[81*35+j],a);
      const int col=(j<3)?j:j+1;
      s_xdbc[l*JPAD+col]=a;
    }
    __syncthreads();
    for (int w=tid;w<TSUB*DIN;w+=256){
      const int l=w&15,dd=w>>4;
      float a=s_dtb[dd];
      a=fmaf(s_xdbc[l*JPAD+0],s_dtw[dd*3+0],a);
      a=fmaf(s_xdbc[l*JPAD+1],s_dtw[dd*3+1],a);
      a=fmaf(s_xdbc[l*JPAD+2],s_dtw[dd*3+2],a);
      s_xs[l*SPAD+dd]=softplusf(a);
    }
    __syncthreads();
    if (tid<DIN){
      const int dd=tid;
#pragma unroll 1
      for (int l=0;l<TSUB;++l){
        const float dl=s_xs[l*SPAD+dd];
        const float xcd=s_xc[l*CPAD+dd];
        const float dxc=dl*xcd;
        const float4 B0=*(const float4*)&s_xdbc[l*JPAD+4];
        const float4 B1=*(const float4*)&s_xdbc[l*JPAD+8];
        const float4 B2=*(const float4*)&s_xdbc[l*JPAD+12];
        const float4 B3=*(const float4*)&s_xdbc[l*JPAD+16];
        const float Bv[NSTATE]={B0.x,B0.y,B0.z,B0.w,B1.x,B1.y,B1.z,B1.w,
                                B2.x,B2.y,B2.z,B2.w,B3.x,B3.y,B3.z,B3.w};
        float Cv[NSTATE];
        if (PASS==3){
          const float4 C0=*(const float4*)&s_xdbc[l*JPAD+20];
          const float4 C1=*(const float4*)&s_xdbc[l*JPAD+24];
          const float4 C2=*(const float4*)&s_xdbc[l*JPAD+28];
          const float4 C3=*(const float4*)&s_xdbc[l*JPAD+32];
          Cv[0]=C0.x;Cv[1]=C0.y;Cv[2]=C0.z;Cv[3]=C0.w;
          Cv[4]=C1.x;Cv[5]=C1.y;Cv[6]=C1.z;Cv[7]=C1.w;
          Cv[8]=C2.x;Cv[9]=C2.y;Cv[10]=C2.z;Cv[11]=C2.w;
          Cv[12]=C3.x;Cv[13]=C3.y;Cv[14]=C3.z;Cv[15]=C3.w;
        }
        float y=(PASS==3)?Dd*xcd:0.f;
        if (structured){
          const float q=expf(dl*A0);
          float e=q;
#pragma unroll
          for (int s=0;s<NSTATE;++s){
            h[s]=fmaf(e,h[s],dxc*Bv[s]);
            if (PASS==1) Pp[s]*=e; else y=fmaf(h[s],Cv[s],y);
            if (s<NSTATE-1) e*=q;
          }
        } else {
#pragma unroll
          for (int s=0;s<NSTATE;++s){
            const float e=expf(dl*As[s]);
            h[s]=fmaf(e,h[s],dxc*Bv[s]);
            if (PASS==1) Pp[s]*=e; else y=fmaf(h[s],Cv[s],y);
          }
        }
        if (PASS==3) s_xs[l*SPAD+dd]=y;
      }
    }
    __syncthreads();
    if (PASS==3){
      for (int w=tid;w<TSUB*DIN;w+=256){
        const int l=w&15,dd=w>>4;
        s_xc[l*CPAD+dd]=s_xs[l*SPAD+dd]*siluf(s_z[l*SPAD+dd]);
      }
      __syncthreads();
      for (int w=tid;w<TSUB*DMODEL;w+=256){
        const int l=w&15,dm=w>>4;
        const float2* wp=(const float2*)(w_out+dm*DIN);
        const float2* gp=(const float2*)&s_xc[l*CPAD];
        float a=0.f;
#pragma unroll
        for (int dq=0;dq<41;++dq){
          const float2 wv=wp[dq], gv=gp[dq];
          a=fmaf(wv.x,gv.x,a); a=fmaf(wv.y,gv.y,a);
        }
        s_x[l*XPAD+dm]=a;
      }
      __syncthreads();
      for (int w=tid;w<TSUB*NLAB;w+=256){
        const int l=w&15,n=w>>4;
        float a=b_cls[n];
#pragma unroll
        for (int dm=0;dm<DMODEL;++dm) a=fmaf(w_cls[n*DMODEL+dm],s_x[l*XPAD+dm],a);
        s_xdbc[l*NLAB+n]=a;
      }
      __syncthreads();
      for (int i=tid;i<TSUB*NLAB;i+=256)
        outg[((size_t)(b*SEQ+p0))*NLAB+i]=s_xdbc[i];
      __syncthreads();
    }
  }

  if (PASS==1 && tid<DIN){
    size_t base=((size_t)(b*NCHUNK+c))*(DIN*NSTATE)+(size_t)tid*NSTATE;
#pragma unroll
    for (int s=0;s<NSTATE;++s){ Pg[base+s]=Pp[s]; Hg[base+s]=h[s]; }
  }
}

__global__ __launch_bounds__(256) void mamba_combine(
    const float* __restrict__ P, const float* __restrict__ H, float* __restrict__ Hin){
  const int g=blockIdx.x*256+threadIdx.x;
  const int b=g/(DIN*NSTATE), ds=g-b*(DIN*NSTATE);
  float h=0.f;
#pragma unroll 1
  for (int c=0;c<NCHUNK;++c){
    const size_t idx=((size_t)(b*NCHUNK+c))*(DIN*NSTATE)+ds;
    Hin[idx]=h;
    h=fmaf(P[idx],h,H[idx]);
  }
}

// ============================================================================

extern "C" void kernel_launch(void* const* d_in, const int* in_sizes, int n_in,
                              void* d_out, int out_size, void* d_ws, size_t ws_size,
                              hipStream_t stream) {
  const float* xg     = (const float*)d_in[0];
  const float* w_in   = (const float*)d_in[1];
  const float* w_conv = (const float*)d_in[2];
  const float* b_conv = (const float*)d_in[3];
  const float* w_xp   = (const float*)d_in[4];
  const float* w_dt   = (const float*)d_in[5];
  const float* b_dt   = (const float*)d_in[6];
  const float* A_log  = (const float*)d_in[7];
  const float* Dv     = (const float*)d_in[8];
  const float* w_out  = (const float*)d_in[9];
  const float* w_cls  = (const float*)d_in[10];
  const float* b_cls  = (const float*)d_in[11];
  float* outg = (float*)d_out;

  int P = 0;
  for (int p : {1,2,4,8}) if (ws_size >= tier_bytes(p)) { P = p; break; }

  if (P) {
    const int SEG = SEQ/P, tiles = SEG/T0;
    const size_t featF = (size_t)BATCH*SEG*FREC;
    const size_t phF   = (size_t)BATCH*tiles*1312;
    float* feat  = (float*)d_ws;
    float* Pg    = feat + featF;
    float* Hg    = Pg + phF;
    float* Hin   = Hg + phF;
    float* carry = Hin + phF;
    float* Mg    = carry + (size_t)BATCH*1312;
    float* wTx   = Mg + 820;
    float* wTz   = wTx + 3362;
    k_pre<<<dim3(32),256,0,stream>>>(w_out, w_cls, w_in, Mg, wTx, wTz);
    for (int p=0;p<P;p++){
      const int off = p*SEG;
      k0_feat<<<dim3(tiles,BATCH),256,0,stream>>>(
          xg,wTx,w_conv,b_conv,w_xp,w_dt,b_dt,A_log,Dv,off,SEG,feat,Pg,Hg);
      k2_comb<<<dim3((BATCH*1312)/256),256,0,stream>>>(Pg,Hg,Hin,carry,tiles,p==0?1:0);
      k4_out<<<dim3(tiles,BATCH),256,0,stream>>>(
          xg,wTz,A_log,Mg,b_cls,off,SEG,feat,Hin,outg);
    }
  } else {
    float* Pg  = (float*)d_ws;
    float* Hg  = Pg + NPH_OLD;
    float* Hin = Hg + NPH_OLD;
    dim3 grid(BATCH*NCHUNK), blk(256);
    mamba_chunk<1><<<grid,blk,0,stream>>>(xg,w_in,w_conv,b_conv,w_xp,w_dt,b_dt,
                                          A_log,Dv,w_out,w_cls,b_cls,Pg,Hg,nullptr,nullptr);
    mamba_combine<<<dim3((BATCH*DIN*NSTATE)/256),blk,0,stream>>>(Pg,Hg,Hin);
    mamba_chunk<3><<<grid,blk,0,stream>>>(xg,w_in,w_conv,b_conv,w_xp,w_dt,b_dt,
                                          A_log,Dv,w_out,w_cls,b_cls,nullptr,nullptr,Hin,outg);
  }
}

// Round 9
// 640.920 us; speedup vs baseline: 3.3589x; 1.9432x over previous
//
#include <hip/hip_runtime.h>
#include <math.h>

// Mamba block, fp32, single-scan + closed-form seeding + fused epilogue.
// k_pre  : M = w_cls@w_out (10x82) into ws.
// k0_feat: features once + local scan -> per-pos (yloc, Dp, C) record staged in
//          LDS, then ONE batched float4 writeout per subtile (full-line writes,
//          no partial-dirty-line RMW). Weights in LDS.
// k2_comb: sequential combine over tiles -> Hin per tile (carry across phases).
// k4_out : z-proj (LDS weights), closed-form corr, gate, fused M-GEMM logits.
// HARD-WON CONSTRAINTS:
//  - launch_bounds (256,4) ONLY: (256,6) capped VGPR->40, spilled scan state,
//    3.3GB scratch (R6). Reg-array weights also spill (R4).
//  - weights MUST be in LDS: global "L1-broadcast" weights miss under feat
//    streaming L2 thrash -> +440MB fetch (R7).
// OLD path (proven): fallback if ws too small.

namespace {
constexpr int DMODEL=41, DIN=82, NSTATE=16, NLAB=10, BATCH=32, SEQ=8192;
// old path
constexpr int CHUNK=512, NCHUNK=SEQ/CHUNK, TSUB=16, NSUB=CHUNK/TSUB, RWS=TSUB+3;
constexpr int XPAD=44, SPAD=83, CPAD=84, JPAD=36;
constexpr int NPH_OLD = BATCH*NCHUNK*DIN*NSTATE;
// new path
constexpr int T0 = 64;              // positions per k0/k4 tile
constexpr int FREC = 180;           // yloc@0(82) | Dp@82(82) | C@164(16)
inline size_t tier_bytes(int P){
  size_t SEG = (size_t)SEQ/P, tiles = SEG/T0;
  return ((size_t)BATCH*SEG*FREC + 3*((size_t)BATCH*tiles*1312)
          + (size_t)BATCH*1312 + 4096)*4;
}
}

__device__ __forceinline__ float siluf(float v)     { return v / (1.f + expf(-v)); }
__device__ __forceinline__ float softplusf(float v) { return (v > 20.f) ? v : log1pf(expf(v)); }
// fast variants (validated R4/R5: absmax unchanged at 5.96e-8)
__device__ __forceinline__ float silu_f(float v){
  return v * __builtin_amdgcn_rcpf(1.f + __expf(-v));
}
__device__ __forceinline__ float softplus_f(float v){
  return (v > 20.f) ? v : __logf(1.f + __expf(v));
}

// in_proj helper: NR rows from r0, col e(<82), weights in LDS [k*82+e],
// x stride 44, out stride 82
template<int NR>
__device__ __forceinline__ void inproj_rows(int r0, int e,
    const float* __restrict__ sx, const float* __restrict__ wt,
    float* __restrict__ sxs) {
  float acc[NR];
#pragma unroll
  for (int i=0;i<NR;i++) acc[i]=0.f;
#pragma unroll
  for (int kq=0;kq<40;kq+=4){
    const float w0=wt[(kq+0)*82+e], w1=wt[(kq+1)*82+e];
    const float w2=wt[(kq+2)*82+e], w3=wt[(kq+3)*82+e];
#pragma unroll
    for (int i=0;i<NR;i++){
      const float4 xv = *(const float4*)&sx[(r0+i)*44+kq];
      acc[i]=fmaf(xv.x,w0,acc[i]); acc[i]=fmaf(xv.y,w1,acc[i]);
      acc[i]=fmaf(xv.z,w2,acc[i]); acc[i]=fmaf(xv.w,w3,acc[i]);
    }
  }
  const float wl = wt[40*82+e];
#pragma unroll
  for (int i=0;i<NR;i++)
    sxs[(r0+i)*82+e] = fmaf(sx[(r0+i)*44+40], wl, acc[i]);
}

// ============================================================================
// NEW PATH
// ============================================================================

__global__ __launch_bounds__(256) void k_pre(
    const float* __restrict__ w_out, const float* __restrict__ w_cls,
    float* __restrict__ M){
  const int w = blockIdx.x*256 + threadIdx.x;
  if (w < NLAB*DIN){
    const int n = w/82, dd = w - n*82;
    float a = 0.f;
#pragma unroll
    for (int dm=0;dm<41;dm++) a = fmaf(w_cls[n*41+dm], w_out[dm*82+dd], a);
    M[w] = a;
  }
}

__launch_bounds__(256, 4)
__global__ void k0_feat(
    const float* __restrict__ xg, const float* __restrict__ w_in,
    const float* __restrict__ w_conv, const float* __restrict__ b_conv,
    const float* __restrict__ w_xproj, const float* __restrict__ w_dt,
    const float* __restrict__ b_dt, const float* __restrict__ A_log,
    const float* __restrict__ Dvec, int off, int SEG,
    float* __restrict__ feat, float* __restrict__ Pg, float* __restrict__ Hg)
{
  __shared__ float s_x[19*44];    // raw x rows (pos p0-3 .. p0+15)
  __shared__ float s_xs[19*82];   // xs rows incl conv halo
  __shared__ float s_xc[16*82];   // xc; scan overwrites with yloc
  __shared__ float s_q[16*82];    // delta; scan overwrites with Dp
  __shared__ float s_db[16*36];   // dt@0..2, B@4..19, C@20..35
  __shared__ float w_t[41*82];    // in_proj xs-half transposed [k][e] (LDS!)
  __shared__ float s_cw[4*82];    // conv w transposed [k][d]
  __shared__ float s_dtw[3*82];   // dt w transposed [k][d]
  __shared__ float s_cb[82], s_dtb[82], s_A0[82], s_Dv[82];
  __shared__ int   s_flag[82];
  // ~39.8 KB -> 4 blocks/CU

  const int tid = threadIdx.x;
  const int tile = blockIdx.x, b = blockIdx.y;
  const int base_pos = off + tile*T0;

  for (int i=tid;i<41*82;i+=256){ int k=i/82,e=i-k*82; w_t[i]=w_in[e*41+k]; }
  for (int i=tid;i<328;i+=256){ int dd=i/4,k=i-dd*4; s_cw[k*82+dd]=w_conv[i]; }
  for (int i=tid;i<246;i+=256){ int dd=i/3,k=i-dd*3; s_dtw[k*82+dd]=w_dt[i]; }
  if (tid<82){
    s_cb[tid]=b_conv[tid]; s_dtb[tid]=b_dt[tid]; s_Dv[tid]=Dvec[tid];
    float A0=-expf(A_log[tid*16]); s_A0[tid]=A0;
    bool ok=(A0<0.f);
#pragma unroll
    for (int s=1;s<16;s++){
      float As=-expf(A_log[tid*16+s]);
      ok = ok && (fabsf(As-(float)(s+1)*A0) <= 1e-3f*(float)(s+1)*fabsf(A0));
    }
    s_flag[tid]=ok?1:0;
  }
  __syncthreads();

  const int d = tid>>1, sg = tid&1;
  float h[8], As[8], A0d=-1.f, Dp=0.f;
  int flag=1;
  if (tid<164){
    flag = s_flag[d]; A0d = s_A0[d];
    if (!flag){
#pragma unroll
      for (int i=0;i<8;i++) As[i]=-expf(A_log[d*16+sg*8+i]);
    }
#pragma unroll
    for (int i=0;i<8;i++) h[i]=0.f;
  }

  for (int it=0; it<T0/16; ++it){
    const int p0 = base_pos + it*16;
    // ---- A: halo shift + raw x load ----
    if (it>0){
      for (int i=tid;i<246;i+=256){ int r=i/82, dd=i-r*82; s_xs[r*82+dd]=s_xs[(16+r)*82+dd]; }
    }
    {
      const int rlo=(it==0)?0:3, cnt=(19-rlo)*41;
      for (int i=tid;i<cnt;i+=256){
        int r=rlo+i/41, k=i-(i/41)*41;
        int pos=p0-3+r;
        s_x[r*44+k] = (pos>=0) ? xg[((size_t)b*SEQ+(size_t)pos)*41+k] : 0.f;
      }
    }
    __syncthreads();
    // ---- B: in_proj (xs half), 2 threads/column, weights in LDS ----
    if (tid<164){
      const int e=(tid<82)?tid:tid-82, rh=(tid>=82);
      if (it==0){ if(!rh) inproj_rows<10>(0,e,s_x,w_t,s_xs); else inproj_rows<9>(10,e,s_x,w_t,s_xs); }
      else      { inproj_rows<8>(rh?11:3,e,s_x,w_t,s_xs); }
    }
    __syncthreads();
    // ---- C: conv + silu -> s_xc ----
    for (int w=tid;w<1312;w+=256){
      const int l=w&15, dd=w>>4;
      float a=s_cb[dd];
#pragma unroll
      for (int k=0;k<4;k++) a=fmaf(s_xs[(l+k)*82+dd], s_cw[k*82+dd], a);
      s_xc[l*82+dd]=silu_f(a);
    }
    __syncthreads();
    // ---- D: x_proj (35 rows) -> dt/B/C in s_db only ----
    for (int w=tid;w<560;w+=256){
      const int l=w&15, j=w>>4;
      const float2* wp=(const float2*)(w_xproj + j*82);
      const float2* gp=(const float2*)&s_xc[l*82];
      float a=0.f;
#pragma unroll
      for (int dq=0;dq<41;dq++){
        const float2 wv=wp[dq], gv=gp[dq];
        a=fmaf(wv.x,gv.x,a); a=fmaf(wv.y,gv.y,a);
      }
      const int col=(j<3)?j:j+1;
      s_db[l*36+col]=a;
    }
    __syncthreads();
    // ---- D2: dt_proj + softplus -> delta ----
    for (int w=tid;w<1312;w+=256){
      const int l=w&15, dd=w>>4;
      float a=s_dtb[dd];
      a=fmaf(s_db[l*36+0],s_dtw[0*82+dd],a);
      a=fmaf(s_db[l*36+1],s_dtw[1*82+dd],a);
      a=fmaf(s_db[l*36+2],s_dtw[2*82+dd],a);
      s_q[l*82+dd]=softplus_f(a);
    }
    __syncthreads();
    // ---- E: local scan; stage yloc into s_xc, Dp into s_q (in place) ----
    if (tid<164){
#pragma unroll 1
      for (int l=0;l<16;l++){
        const float dl  = s_q[l*82+d];
        const float xc  = s_xc[l*82+d];
        const float dxc = dl*xc;
        Dp += dl;
        const float4 B0=*(const float4*)&s_db[l*36+4+sg*8];
        const float4 B1=*(const float4*)&s_db[l*36+8+sg*8];
        const float4 C0=*(const float4*)&s_db[l*36+20+sg*8];
        const float4 C1=*(const float4*)&s_db[l*36+24+sg*8];
        const float Bv[8]={B0.x,B0.y,B0.z,B0.w,B1.x,B1.y,B1.z,B1.w};
        const float Cv[8]={C0.x,C0.y,C0.z,C0.w,C1.x,C1.y,C1.z,C1.w};
        float y=0.f;
        if (flag){
          const float q=__expf(dl*A0d);
          const float q2=q*q, q4=q2*q2;
          float e = sg ? q4*q4*q : q;
#pragma unroll
          for (int s=0;s<8;s++){
            h[s]=fmaf(e,h[s],dxc*Bv[s]);
            y=fmaf(h[s],Cv[s],y);
            if(s<7) e*=q;
          }
        } else {
#pragma unroll
          for (int s=0;s<8;s++){
            const float e=__expf(dl*As[s]);
            h[s]=fmaf(e,h[s],dxc*Bv[s]);
            y=fmaf(h[s],Cv[s],y);
          }
        }
        y += __shfl_down(y,1);
        if (sg==0){
          // pair lanes are lockstep: both read xc/dl above before these writes
          s_xc[l*82+d] = y + xc*s_Dv[d];   // yloc
          s_q [l*82+d] = Dp;               // prefix-sum of delta
        }
      }
    }
    __syncthreads();
    // ---- F: batched record writeout (720 float4 = 16 recs x 180 floats) ----
    {
      float* fb = feat + ((size_t)b*SEG + (size_t)(tile*T0+it*16))*FREC;
      for (int i=tid;i<720;i+=256){
        const int l=i/45, q=i-l*45;
        const int f=4*q;
        float4 v;
        if (q<20){
          v.x=s_xc[l*82+f+0]; v.y=s_xc[l*82+f+1];
          v.z=s_xc[l*82+f+2]; v.w=s_xc[l*82+f+3];
        } else if (q==20){
          v.x=s_xc[l*82+80]; v.y=s_xc[l*82+81];
          v.z=s_q[l*82+0];   v.w=s_q[l*82+1];
        } else if (q<=40){
          v.x=s_q[l*82+f-82]; v.y=s_q[l*82+f-81];
          v.z=s_q[l*82+f-80]; v.w=s_q[l*82+f-79];
        } else {
          const int c=f-164;
          v.x=s_db[l*36+20+c+0]; v.y=s_db[l*36+20+c+1];
          v.z=s_db[l*36+20+c+2]; v.w=s_db[l*36+20+c+3];
        }
        *(float4*)&fb[(size_t)l*FREC + f] = v;
      }
    }
    // no trailing barrier: next C/D2 writes to s_xc/s_q are 2+ barriers away
  }

  if (tid<164){
    float Pv[8];
    if (flag){
      const float Qt=__expf(Dp*A0d);
      const float Q2=Qt*Qt, Q4=Q2*Q2, Q8=Q4*Q4;
      float c = sg ? Q8*Qt : Qt;
#pragma unroll
      for (int i=0;i<8;i++){ Pv[i]=c; c*=Qt; }
    } else {
#pragma unroll
      for (int i=0;i<8;i++) Pv[i]=__expf(Dp*As[i]);
    }
    const size_t base = ((size_t)(b*gridDim.x+tile))*1312 + (size_t)d*16 + sg*8;
    *(float4*)&Pg[base]   = make_float4(Pv[0],Pv[1],Pv[2],Pv[3]);
    *(float4*)&Pg[base+4] = make_float4(Pv[4],Pv[5],Pv[6],Pv[7]);
    *(float4*)&Hg[base]   = make_float4(h[0],h[1],h[2],h[3]);
    *(float4*)&Hg[base+4] = make_float4(h[4],h[5],h[6],h[7]);
  }
}

__global__ __launch_bounds__(256) void k2_comb(
    const float* __restrict__ Pg, const float* __restrict__ Hg,
    float* __restrict__ Hin, float* __restrict__ carry, int TPP, int first)
{
  const int g = blockIdx.x*256 + threadIdx.x;   // < 32*1312
  const int b = g/1312, r = g - b*1312;
  float h = first ? 0.f : carry[g];
#pragma unroll 4
  for (int t=0;t<TPP;t++){
    const size_t idx = ((size_t)(b*TPP+t))*1312 + r;
    Hin[idx]=h;
    h = fmaf(Pg[idx], h, Hg[idx]);
  }
  carry[g]=h;
}

__launch_bounds__(256, 4)
__global__ void k4_out(
    const float* __restrict__ xg, const float* __restrict__ w_in,
    const float* __restrict__ A_log, const float* __restrict__ Mg,
    const float* __restrict__ b_cls, int off, int SEG,
    const float* __restrict__ feat, const float* __restrict__ Hin,
    float* __restrict__ outg)
{
  __shared__ float s_x[16*44];    // raw x rows
  __shared__ float w_zt[41*82];   // in_proj z-half transposed [k][e] (LDS!)
  __shared__ float s_z[16*82];    // silu(z)
  __shared__ float s_g[16*82];    // gated value
  __shared__ float s_c[16*16];    // C rows
  __shared__ float s_hin[1312];   // s-major [s*82+d]
  __shared__ float s_M[10*82];    // fused Wc*Wo
  __shared__ float s_A0[82], s_bc[10];
  __shared__ int   s_flag[82];
  // ~37.1 KB -> 4 blocks/CU

  const int tid = threadIdx.x;
  const int tile = blockIdx.x, b = blockIdx.y;

  for (int i=tid;i<41*82;i+=256){ int k=i/82,e=i-k*82; w_zt[i]=w_in[(82+e)*41+k]; }
  for (int i=tid;i<1312;i+=256){
    const int dd=i>>4, s=i&15;
    s_hin[s*82+dd] = Hin[((size_t)(b*gridDim.x+tile))*1312 + i];
  }
  for (int i=tid;i<820;i+=256) s_M[i]=Mg[i];
  if (tid<10) s_bc[tid]=b_cls[tid];
  if (tid<82){
    float A0=-expf(A_log[tid*16]); s_A0[tid]=A0;
    bool ok=(A0<0.f);
#pragma unroll
    for (int s=1;s<16;s++){
      float As=-expf(A_log[tid*16+s]);
      ok = ok && (fabsf(As-(float)(s+1)*A0) <= 1e-3f*(float)(s+1)*fabsf(A0));
    }
    s_flag[tid]=ok?1:0;
  }
  // hoisted (l,d) decomposition for the 1312-item stage
  int lk[6], dk[6];
#pragma unroll
  for (int k=0;k<6;k++){ const int w=tid+256*k; lk[k]=w/82; dk[k]=w-lk[k]*82; }

  for (int it=0; it<T0/16; ++it){
    const int lp0 = tile*T0 + it*16;
    const int gp0 = off + lp0;
    __syncthreads();
    // ---- A: load raw x + C rows ----
    for (int i=tid;i<656;i+=256){
      const int r=i/41, k=i-r*41;
      s_x[r*44+k] = xg[((size_t)b*SEQ+(size_t)(gp0+r))*41+k];
    }
    for (int i=tid;i<64;i+=256){
      const int l=i>>2, q=i&3;
      ((float4*)&s_c[l*16])[q] =
          ((const float4*)(feat + ((size_t)b*SEG+(size_t)(lp0+l))*FREC + 164))[q];
    }
    __syncthreads();
    // ---- B: z-proj (LDS weights), 2 threads/column, 8 rows -> silu ----
    if (tid<164){
      const int e=(tid<82)?tid:tid-82, l0=(tid>=82)?8:0;
      float acc[8];
#pragma unroll
      for (int i=0;i<8;i++) acc[i]=0.f;
#pragma unroll
      for (int kq=0;kq<40;kq+=4){
        const float w0=w_zt[(kq+0)*82+e], w1=w_zt[(kq+1)*82+e];
        const float w2=w_zt[(kq+2)*82+e], w3=w_zt[(kq+3)*82+e];
#pragma unroll
        for (int i=0;i<8;i++){
          const float4 xv=*(const float4*)&s_x[(l0+i)*44+kq];
          acc[i]=fmaf(xv.x,w0,acc[i]); acc[i]=fmaf(xv.y,w1,acc[i]);
          acc[i]=fmaf(xv.z,w2,acc[i]); acc[i]=fmaf(xv.w,w3,acc[i]);
        }
      }
      const float wl=w_zt[40*82+e];
#pragma unroll
      for (int i=0;i<8;i++)
        s_z[(l0+i)*82+e] = silu_f(fmaf(s_x[(l0+i)*44+40], wl, acc[i]));
    }
    __syncthreads();
    // ---- C: closed-form correction + gate ----
#pragma unroll
    for (int k=0;k<6;k++){
      const int w=tid+256*k;
      if (w>=1312) break;
      const int l=lk[k], dd=dk[k];
      const float* fp = feat + ((size_t)b*SEG+(size_t)(lp0+l))*FREC;
      const float yl = fp[dd];
      const float Dp = fp[82+dd];
      float acc=yl;
      if (s_flag[dd]){
        const float Qt=__expf(s_A0[dd]*Dp);
        float e=Qt;
#pragma unroll
        for (int s=0;s<16;s++){
          acc = fmaf(s_c[l*16+s]*e, s_hin[s*82+dd], acc);
          if (s<15) e*=Qt;
        }
      } else {
#pragma unroll
        for (int s=0;s<16;s++){
          const float As = -__expf(A_log[dd*16+s]);
          acc = fmaf(s_c[l*16+s]*__expf(As*Dp), s_hin[s*82+dd], acc);
        }
      }
      s_g[l*82+dd] = acc * s_z[l*82+dd];
    }
    __syncthreads();
    // ---- D: fused logits = M*g + b, contiguous store ----
    if (tid<160){
      const int l=tid/10, n=tid-(tid/10)*10;
      float a=s_bc[n];
      const float2* gp=(const float2*)&s_g[l*82];
      const float2* mp=(const float2*)&s_M[n*82];
#pragma unroll
      for (int q=0;q<41;q++){
        const float2 gv=gp[q], mv=mp[q];
        a=fmaf(gv.x,mv.x,a); a=fmaf(gv.y,mv.y,a);
      }
      outg[((size_t)b*SEQ+(size_t)gp0)*10 + tid] = a;
    }
    // no trailing barrier: top-of-loop sync protects s_x/s_c overwrite
  }
}

// ============================================================================
// OLD PATH (proven fallback)
// ============================================================================

template <int PASS>
__launch_bounds__(256, 2)
__global__ void mamba_chunk(
    const float* __restrict__ xg, const float* __restrict__ w_in,
    const float* __restrict__ w_conv, const float* __restrict__ b_conv,
    const float* __restrict__ w_xproj, const float* __restrict__ w_dt,
    const float* __restrict__ b_dt, const float* __restrict__ A_log,
    const float* __restrict__ Dvec, const float* __restrict__ w_out,
    const float* __restrict__ w_cls, const float* __restrict__ b_cls,
    float* __restrict__ Pg, float* __restrict__ Hg,
    const float* __restrict__ Hin, float* __restrict__ outg)
{
  __shared__ float s_x[RWS*XPAD];
  __shared__ float s_xs[RWS*SPAD];
  __shared__ float s_xc[TSUB*CPAD];
  __shared__ float s_z[TSUB*SPAD];
  __shared__ float s_xdbc[TSUB*JPAD];
  __shared__ float w_in_t[DMODEL*164];
  __shared__ float w_xp_t[DIN*35];
  __shared__ float s_cw[DIN*4];
  __shared__ float s_cb[DIN];
  __shared__ float s_dtw[DIN*3];
  __shared__ float s_dtb[DIN];

  const int tid=threadIdx.x;
  const int b=blockIdx.x/NCHUNK, c=blockIdx.x%NCHUNK, l0c=c*CHUNK;
  constexpr int NJ=(PASS==3)?35:19;
  constexpr int NE=(PASS==3)?164:DIN;

  for (int i=tid;i<DMODEL*164;i+=256){ int k=i/164,e=i-k*164; w_in_t[i]=w_in[e*DMODEL+k]; }
  for (int i=tid;i<DIN*35;i+=256){ int dd=i/35,j=i-dd*35; w_xp_t[i]=w_xproj[j*DIN+dd]; }
  for (int i=tid;i<DIN*4;i+=256) s_cw[i]=w_conv[i];
  for (int i=tid;i<DIN*3;i+=256) s_dtw[i]=w_dt[i];
  if (tid<DIN){ s_cb[tid]=b_conv[tid]; s_dtb[tid]=b_dt[tid]; }

  float h[NSTATE], Pp[NSTATE], As[NSTATE];
  float A0=-1.f, Dd=0.f;
  bool structured=true;
  if (tid<DIN){
#pragma unroll
    for (int s=0;s<NSTATE;++s) As[s]=-expf(A_log[tid*NSTATE+s]);
    A0=As[0];
#pragma unroll
    for (int s=0;s<NSTATE;++s)
      structured = structured && (fabsf(As[s]-(float)(s+1)*A0)<=1e-3f*(float)(s+1)*fabsf(A0));
    structured = structured && (A0<0.f);
    if (PASS==3){
      Dd=Dvec[tid];
      size_t base=((size_t)(b*NCHUNK+c))*(DIN*NSTATE)+(size_t)tid*NSTATE;
#pragma unroll
      for (int s=0;s<NSTATE;++s) h[s]=Hin[base+s];
    } else {
#pragma unroll
      for (int s=0;s<NSTATE;++s){ h[s]=0.f; Pp[s]=1.f; }
    }
  }
  __syncthreads();

  for (int t=0;t<NSUB;++t){
    const int p0=l0c+t*TSUB;
    for (int i=tid;i<RWS*DMODEL;i+=256){
      int r=i/DMODEL,k=i-r*DMODEL;
      int pos=p0-3+r;
      s_x[r*XPAD+k]=(pos>=0)?xg[(size_t)b*SEQ*DMODEL+(size_t)pos*DMODEL+k]:0.f;
    }
    __syncthreads();
    {
      const int e=tid;
      if (e<NE){
        float acc[RWS];
#pragma unroll
        for (int r=0;r<RWS;++r) acc[r]=0.f;
#pragma unroll
        for (int kq=0;kq<40;kq+=4){
          const float w0=w_in_t[(kq+0)*164+e], w1=w_in_t[(kq+1)*164+e];
          const float w2=w_in_t[(kq+2)*164+e], w3=w_in_t[(kq+3)*164+e];
#pragma unroll
          for (int r=0;r<RWS;++r){
            const float4 xv=*(const float4*)&s_x[r*XPAD+kq];
            acc[r]=fmaf(xv.x,w0,acc[r]); acc[r]=fmaf(xv.y,w1,acc[r]);
            acc[r]=fmaf(xv.z,w2,acc[r]); acc[r]=fmaf(xv.w,w3,acc[r]);
          }
        }
        const float wl=w_in_t[40*164+e];
#pragma unroll
        for (int r=0;r<RWS;++r) acc[r]=fmaf(s_x[r*XPAD+40],wl,acc[r]);
        if (e<DIN){
#pragma unroll
          for (int r=0;r<RWS;++r) s_xs[r*SPAD+e]=acc[r];
        } else {
#pragma unroll
          for (int r=3;r<RWS;++r) s_z[(r-3)*SPAD+(e-DIN)]=acc[r];
        }
      }
    }
    __syncthreads();
    for (int w=tid;w<TSUB*DIN;w+=256){
      const int l=w&15,e=w>>4;
      float a=s_cb[e];
#pragma unroll
      for (int k=0;k<4;++k) a=fmaf(s_xs[(l+k)*SPAD+e],s_cw[e*4+k],a);
      s_xc[l*CPAD+e]=siluf(a);
    }
    __syncthreads();
    for (int w=tid;w<TSUB*NJ;w+=256){
      const int l=w&15,j=w>>4;
      float a=0.f;
#pragma unroll
      for (int dq=0;dq<80;dq+=4){
        const float4 xv=*(const float4*)&s_xc[l*CPAD+dq];
        a=fmaf(xv.x,w_xp_t[(dq+0)*35+j],a); a=fmaf(xv.y,w_xp_t[(dq+1)*35+j],a);
        a=fmaf(xv.z,w_xp_t[(dq+2)*35+j],a); a=fmaf(xv.w,w_xp_t[(dq+3)*35+j],a);
      }
      a=fmaf(s_xc[l*CPAD+80],w_xp_t[80*35+j],a);
      a=fmaf(s_xc[l*CPAD+81],w_xp_t[81*35+j],a);
      const int col=(j<3)?j:j+1;
      s_xdbc[l*JPAD+col]=a;
    }
    __syncthreads();
    for (int w=tid;w<TSUB*DIN;w+=256){
      const int l=w&15,dd=w>>4;
      float a=s_dtb[dd];
      a=fmaf(s_xdbc[l*JPAD+0],s_dtw[dd*3+0],a);
      a=fmaf(s_xdbc[l*JPAD+1],s_dtw[dd*3+1],a);
      a=fmaf(s_xdbc[l*JPAD+2],s_dtw[dd*3+2],a);
      s_xs[l*SPAD+dd]=softplusf(a);
    }
    __syncthreads();
    if (tid<DIN){
      const int dd=tid;
#pragma unroll 1
      for (int l=0;l<TSUB;++l){
        const float dl=s_xs[l*SPAD+dd];
        const float xcd=s_xc[l*CPAD+dd];
        const float dxc=dl*xcd;
        const float4 B0=*(const float4*)&s_xdbc[l*JPAD+4];
        const float4 B1=*(const float4*)&s_xdbc[l*JPAD+8];
        const float4 B2=*(const float4*)&s_xdbc[l*JPAD+12];
        const float4 B3=*(const float4*)&s_xdbc[l*JPAD+16];
        const float Bv[NSTATE]={B0.x,B0.y,B0.z,B0.w,B1.x,B1.y,B1.z,B1.w,
                                B2.x,B2.y,B2.z,B2.w,B3.x,B3.y,B3.z,B3.w};
        float Cv[NSTATE];
        if (PASS==3){
          const float4 C0=*(const float4*)&s_xdbc[l*JPAD+20];
          const float4 C1=*(const float4*)&s_xdbc[l*JPAD+24];
          const float4 C2=*(const float4*)&s_xdbc[l*JPAD+28];
          const float4 C3=*(const float4*)&s_xdbc[l*JPAD+32];
          Cv[0]=C0.x;Cv[1]=C0.y;Cv[2]=C0.z;Cv[3]=C0.w;
          Cv[4]=C1.x;Cv[5]=C1.y;Cv[6]=C1.z;Cv[7]=C1.w;
          Cv[8]=C2.x;Cv[9]=C2.y;Cv[10]=C2.z;Cv[11]=C2.w;
          Cv[12]=C3.x;Cv[13]=C3.y;Cv[14]=C3.z;Cv[15]=C3.w;
        }
        float y=(PASS==3)?Dd*xcd:0.f;
        if (structured){
          const float q=expf(dl*A0);
          float e=q;
#pragma unroll
          for (int s=0;s<NSTATE;++s){
            h[s]=fmaf(e,h[s],dxc*Bv[s]);
            if (PASS==1) Pp[s]*=e; else y=fmaf(h[s],Cv[s],y);
            if (s<NSTATE-1) e*=q;
          }
        } else {
#pragma unroll
          for (int s=0;s<NSTATE;++s){
            const float e=expf(dl*As[s]);
            h[s]=fmaf(e,h[s],dxc*Bv[s]);
            if (PASS==1) Pp[s]*=e; else y=fmaf(h[s],Cv[s],y);
          }
        }
        if (PASS==3) s_xs[l*SPAD+dd]=y;
      }
    }
    __syncthreads();
    if (PASS==3){
      for (int w=tid;w<TSUB*DIN;w+=256){
        const int l=w&15,dd=w>>4;
        s_xc[l*CPAD+dd]=s_xs[l*SPAD+dd]*siluf(s_z[l*SPAD+dd]);
      }
      __syncthreads();
      for (int w=tid;w<TSUB*DMODEL;w+=256){
        const int l=w&15,dm=w>>4;
        const float2* wp=(const float2*)(w_out+dm*DIN);
        const float2* gp=(const float2*)&s_xc[l*CPAD];
        float a=0.f;
#pragma unroll
        for (int dq=0;dq<41;++dq){
          const float2 wv=wp[dq], gv=gp[dq];
          a=fmaf(wv.x,gv.x,a); a=fmaf(wv.y,gv.y,a);
        }
        s_x[l*XPAD+dm]=a;
      }
      __syncthreads();
      for (int w=tid;w<TSUB*NLAB;w+=256){
        const int l=w&15,n=w>>4;
        float a=b_cls[n];
#pragma unroll
        for (int dm=0;dm<DMODEL;++dm) a=fmaf(w_cls[n*DMODEL+dm],s_x[l*XPAD+dm],a);
        s_xdbc[l*NLAB+n]=a;
      }
      __syncthreads();
      for (int i=tid;i<TSUB*NLAB;i+=256)
        outg[((size_t)(b*SEQ+p0))*NLAB+i]=s_xdbc[i];
      __syncthreads();
    }
  }

  if (PASS==1 && tid<DIN){
    size_t base=((size_t)(b*NCHUNK+c))*(DIN*NSTATE)+(size_t)tid*NSTATE;
#pragma unroll
    for (int s=0;s<NSTATE;++s){ Pg[base+s]=Pp[s]; Hg[base+s]=h[s]; }
  }
}

__global__ __launch_bounds__(256) void mamba_combine(
    const float* __restrict__ P, const float* __restrict__ H, float* __restrict__ Hin){
  const int g=blockIdx.x*256+threadIdx.x;
  const int b=g/(DIN*NSTATE), ds=g-b*(DIN*NSTATE);
  float h=0.f;
#pragma unroll 1
  for (int c=0;c<NCHUNK;++c){
    const size_t idx=((size_t)(b*NCHUNK+c))*(DIN*NSTATE)+ds;
    Hin[idx]=h;
    h=fmaf(P[idx],h,H[idx]);
  }
}

// ============================================================================

extern "C" void kernel_launch(void* const* d_in, const int* in_sizes, int n_in,
                              void* d_out, int out_size, void* d_ws, size_t ws_size,
                              hipStream_t stream) {
  const float* xg     = (const float*)d_in[0];
  const float* w_in   = (const float*)d_in[1];
  const float* w_conv = (const float*)d_in[2];
  const float* b_conv = (const float*)d_in[3];
  const float* w_xp   = (const float*)d_in[4];
  const float* w_dt   = (const float*)d_in[5];
  const float* b_dt   = (const float*)d_in[6];
  const float* A_log  = (const float*)d_in[7];
  const float* Dv     = (const float*)d_in[8];
  const float* w_out  = (const float*)d_in[9];
  const float* w_cls  = (const float*)d_in[10];
  const float* b_cls  = (const float*)d_in[11];
  float* outg = (float*)d_out;

  int P = 0;
  for (int p : {1,2,4,8}) if (ws_size >= tier_bytes(p)) { P = p; break; }

  if (P) {
    const int SEG = SEQ/P, tiles = SEG/T0;
    const size_t featF = (size_t)BATCH*SEG*FREC;
    const size_t phF   = (size_t)BATCH*tiles*1312;
    float* feat  = (float*)d_ws;
    float* Pg    = feat + featF;
    float* Hg    = Pg + phF;
    float* Hin   = Hg + phF;
    float* carry = Hin + phF;
    float* Mg    = carry + (size_t)BATCH*1312;
    k_pre<<<dim3(4),256,0,stream>>>(w_out, w_cls, Mg);
    for (int p=0;p<P;p++){
      const int off = p*SEG;
      k0_feat<<<dim3(tiles,BATCH),256,0,stream>>>(
          xg,w_in,w_conv,b_conv,w_xp,w_dt,b_dt,A_log,Dv,off,SEG,feat,Pg,Hg);
      k2_comb<<<dim3((BATCH*1312)/256),256,0,stream>>>(Pg,Hg,Hin,carry,tiles,p==0?1:0);
      k4_out<<<dim3(tiles,BATCH),256,0,stream>>>(
          xg,w_in,A_log,Mg,b_cls,off,SEG,feat,Hin,outg);
    }
  } else {
    float* Pg  = (float*)d_ws;
    float* Hg  = Pg + NPH_OLD;
    float* Hin = Hg + NPH_OLD;
    dim3 grid(BATCH*NCHUNK), blk(256);
    mamba_chunk<1><<<grid,blk,0,stream>>>(xg,w_in,w_conv,b_conv,w_xp,w_dt,b_dt,
                                          A_log,Dv,w_out,w_cls,b_cls,Pg,Hg,nullptr,nullptr);
    mamba_combine<<<dim3((BATCH*DIN*NSTATE)/256),blk,0,stream>>>(Pg,Hg,Hin);
    mamba_chunk<3><<<grid,blk,0,stream>>>(xg,w_in,w_conv,b_conv,w_xp,w_dt,b_dt,
                                          A_log,Dv,w_out,w_cls,b_cls,nullptr,nullptr,Hin,outg);
  }
}